// Round 1
// baseline (1900.943 us; speedup 1.0000x reference)
//
#include <hip/hip_runtime.h>

// Problem constants
constexpr int kB  = 4;
constexpr int kT  = 16;
constexpr int kN  = 4096;
constexpr int kBN = kB * kN;      // 16384
constexpr int kE  = 32768;
constexpr int kH  = 64;
constexpr int kNC = 13;

__device__ __forceinline__ float rl(float v, int l) {
  return __int_as_float(__builtin_amdgcn_readlane(__float_as_int(v), l));
}
__device__ __forceinline__ float sigm(float x) { return 1.f / (1.f + __expf(-x)); }
__device__ __forceinline__ float tanh_(float x) {
  float e = __expf(2.f * x);
  return 1.f - 2.f / (e + 1.f);
}

// ---------------------------------------------------------------------------
// Stage 1: per-node 2-layer MLP (8 -> 64 relu -> 64)
// writes h in layout (t, b*N+n, 64)
// ---------------------------------------------------------------------------
__global__ __launch_bounds__(256) void conv_kernel(
    const float* __restrict__ nf, const float* __restrict__ w1,
    const float* __restrict__ b1, const float* __restrict__ w2,
    const float* __restrict__ b2, float* __restrict__ hout) {
  __shared__ float w1T[8 * 64];    // [f][h]
  __shared__ float w2T[64 * 64];   // [h][g]
  int tid = threadIdx.x;
  for (int i = tid; i < 8 * 64; i += 256) { int h = i >> 3, f = i & 7; w1T[f * 64 + h] = w1[i]; }
  for (int i = tid; i < 64 * 64; i += 256) { int g = i >> 6, h = i & 63; w2T[h * 64 + g] = w2[i]; }
  __syncthreads();
  int lane = tid & 63;
  int node = blockIdx.x * 4 + (tid >> 6);      // flat (b,t,n)
  int b = node >> 16;                          // / (16*4096)
  int t = (node >> 12) & 15;
  int n = node & 4095;
  const float* src = nf + (size_t)node * 8;
  float v = (lane < 8) ? src[lane] : 0.f;
  float h1 = b1[lane];
#pragma unroll
  for (int f = 0; f < 8; ++f) h1 += w1T[f * 64 + lane] * rl(v, f);
  h1 = fmaxf(h1, 0.f);
  float h2 = b2[lane];
#pragma unroll 16
  for (int k = 0; k < 64; ++k) h2 += w2T[k * 64 + lane] * rl(h1, k);
  hout[((size_t)t * kBN + b * kN + n) * 64 + lane] = h2;
}

// ---------------------------------------------------------------------------
// Stage 2a: edge scatter (atomics) -> ssum, cnt
// ---------------------------------------------------------------------------
__global__ __launch_bounds__(256) void scatter_kernel(
    const float* __restrict__ h, const int* __restrict__ ei,
    float* __restrict__ ssum, int* __restrict__ cnt) {
  int tid = threadIdx.x;
  int inst = blockIdx.x * 4 + (tid >> 6);  // 0 .. T*E-1
  int t = inst >> 15;                      // / 32768
  int e = inst & 32767;
  int src = ei[t * 2 * kE + e];
  int dst = ei[t * 2 * kE + kE + e];
  int lane = tid & 63;
  if (lane == 0) atomicAdd(&cnt[t * kN + dst], 1);
  const float* hb = h + (size_t)t * kBN * 64;
  float* sb = ssum + (size_t)t * kBN * 64;
#pragma unroll
  for (int b = 0; b < 4; ++b) {
    float val = hb[((size_t)b * kN + src) * 64 + lane];
    atomicAdd(&sb[((size_t)b * kN + dst) * 64 + lane], val);
  }
}

// ---------------------------------------------------------------------------
// Stage 2b: combine h_new = cnt>0 ? (h + ssum/cnt)*0.5 : h
// ---------------------------------------------------------------------------
__global__ __launch_bounds__(256) void combine_kernel(
    const float* __restrict__ h, const float* __restrict__ ssum,
    const int* __restrict__ cnt, float* __restrict__ x) {
  int i = blockIdx.x * 256 + threadIdx.x;   // over T*BN*16 float4s
  int t = i >> 18;                          // / (BN*16)
  int bn = (i >> 4) & (kBN - 1);
  int n = bn & (kN - 1);
  int c = cnt[t * kN + n];
  float4 hv = ((const float4*)h)[i];
  float4 o;
  if (c > 0) {
    float4 sv = ((const float4*)ssum)[i];
    float inv = 1.f / (float)c;
    o.x = (hv.x + sv.x * inv) * 0.5f;
    o.y = (hv.y + sv.y * inv) * 0.5f;
    o.z = (hv.z + sv.z * inv) * 0.5f;
    o.w = (hv.w + sv.w * inv) * 0.5f;
  } else {
    o = hv;
  }
  ((float4*)x)[i] = o;
}

// ---------------------------------------------------------------------------
// Stage 3: one LSTM layer, persistent over t.
// block = 1024 thr = 16 waves; wave = 4 sequences; lane = channel m.
// LDS: wpack[k][m][g] (k<64: w_ih, k>=64: w_hh), 128 KB.
// ---------------------------------------------------------------------------
__global__ __launch_bounds__(1024) void lstm_kernel(
    const float* __restrict__ xin, float* __restrict__ xout,
    const float* __restrict__ wih, const float* __restrict__ whh,
    const float* __restrict__ bih, const float* __restrict__ bhh) {
  __shared__ __align__(16) float wpack[128 * 64 * 4];  // 131072 B
  int tid = threadIdx.x;
  for (int idx = tid; idx < 16384; idx += 1024) {      // 256x64 each
    int j = idx >> 6, k = idx & 63;
    int g = j >> 6, m = j & 63;
    wpack[((k * 64 + m) << 2) + g] = wih[idx];
    wpack[(((k + 64) * 64 + m) << 2) + g] = whh[idx];
  }
  __syncthreads();
  int wave = tid >> 6, m = tid & 63;
  int s0 = blockIdx.x * 64 + wave * 4;
  float bsum[4];
#pragma unroll
  for (int g = 0; g < 4; ++g) bsum[g] = bih[g * 64 + m] + bhh[g * 64 + m];
  float hr[4] = {0.f, 0.f, 0.f, 0.f};
  float cr[4] = {0.f, 0.f, 0.f, 0.f};
  for (int t = 0; t < kT; ++t) {
    const float* xr = xin + ((size_t)t * kBN + s0) * 64 + m;
    float x0 = xr[0], x1 = xr[64], x2 = xr[128], x3 = xr[192];
    float z[4][4];
#pragma unroll
    for (int i = 0; i < 4; ++i)
#pragma unroll
      for (int g = 0; g < 4; ++g) z[i][g] = bsum[g];
    // input contribution: z += x @ w_ih^T
#pragma unroll 16
    for (int k = 0; k < 64; ++k) {
      float4 w = *(const float4*)&wpack[(k * 64 + m) << 2];
      float a0 = rl(x0, k), a1 = rl(x1, k), a2 = rl(x2, k), a3 = rl(x3, k);
      z[0][0] += w.x * a0; z[0][1] += w.y * a0; z[0][2] += w.z * a0; z[0][3] += w.w * a0;
      z[1][0] += w.x * a1; z[1][1] += w.y * a1; z[1][2] += w.z * a1; z[1][3] += w.w * a1;
      z[2][0] += w.x * a2; z[2][1] += w.y * a2; z[2][2] += w.z * a2; z[2][3] += w.w * a2;
      z[3][0] += w.x * a3; z[3][1] += w.y * a3; z[3][2] += w.z * a3; z[3][3] += w.w * a3;
    }
    // recurrent contribution: z += h @ w_hh^T
#pragma unroll 16
    for (int k = 0; k < 64; ++k) {
      float4 w = *(const float4*)&wpack[((k + 64) * 64 + m) << 2];
      float a0 = rl(hr[0], k), a1 = rl(hr[1], k), a2 = rl(hr[2], k), a3 = rl(hr[3], k);
      z[0][0] += w.x * a0; z[0][1] += w.y * a0; z[0][2] += w.z * a0; z[0][3] += w.w * a0;
      z[1][0] += w.x * a1; z[1][1] += w.y * a1; z[1][2] += w.z * a1; z[1][3] += w.w * a1;
      z[2][0] += w.x * a2; z[2][1] += w.y * a2; z[2][2] += w.z * a2; z[2][3] += w.w * a2;
      z[3][0] += w.x * a3; z[3][1] += w.y * a3; z[3][2] += w.z * a3; z[3][3] += w.w * a3;
    }
    float* yo = xout + ((size_t)t * kBN + s0) * 64 + m;
#pragma unroll
    for (int i = 0; i < 4; ++i) {
      float ig = sigm(z[i][0]);
      float fg = sigm(z[i][1]);
      float gg = tanh_(z[i][2]);
      float og = sigm(z[i][3]);
      cr[i] = fg * cr[i] + ig * gg;
      hr[i] = og * tanh_(cr[i]);
      yo[i * 64] = hr[i];
    }
  }
}

// ---------------------------------------------------------------------------
// Stage 4: attention (last-query only) + out-proj + 3-layer MLP head, fused.
// block = 1024 thr = 16 waves; wave handles 4 sequences sequentially.
// ---------------------------------------------------------------------------
__global__ __launch_bounds__(1024) void head_kernel(
    const float* __restrict__ x, const float* __restrict__ win,
    const float* __restrict__ bin, const float* __restrict__ wout,
    const float* __restrict__ bout, const float* __restrict__ pw1,
    const float* __restrict__ pb1, const float* __restrict__ pw2,
    const float* __restrict__ pb2, const float* __restrict__ pw3,
    const float* __restrict__ pb3, float* __restrict__ out) {
  __shared__ float qT[64 * 64];                  // [k][c]
  __shared__ __align__(8) float kvT[64 * 64 * 2];  // [k][c][{k,v}]
  __shared__ float oT[64 * 64];                  // [k][c]
  __shared__ float w1T[64 * 128];                // [k][j]
  __shared__ float w2T[128 * 64];                // [k][c]
  __shared__ float w3T[64 * 16];                 // [k][c<16]
  int tid = threadIdx.x;
  for (int i = tid; i < 4096; i += 1024) {
    int r = i >> 6, k = i & 63;
    qT[k * 64 + r] = win[r * 64 + k];
    kvT[(k * 64 + r) * 2 + 0] = win[(64 + r) * 64 + k];
    kvT[(k * 64 + r) * 2 + 1] = win[(128 + r) * 64 + k];
    oT[k * 64 + r] = wout[r * 64 + k];
  }
  for (int i = tid; i < 8192; i += 1024) {  // pw1 (128,64)
    int j = i >> 6, k = i & 63;
    w1T[k * 128 + j] = pw1[i];
  }
  for (int i = tid; i < 8192; i += 1024) {  // pw2 (64,128)
    int r = i >> 7, k = i & 127;
    w2T[k * 64 + r] = pw2[i];
  }
  for (int i = tid; i < 1024; i += 1024) {
    int k = i >> 4, c = i & 15;
    w3T[i] = (c < 13) ? pw3[c * 64 + k] : 0.f;
  }
  __syncthreads();
  int wave = tid >> 6, c = tid & 63;
  for (int it = 0; it < 4; ++it) {
    int s = blockIdx.x * 64 + wave * 4 + it;
    float xr[16];
#pragma unroll
    for (int t = 0; t < 16; ++t) xr[t] = x[((size_t)t * kBN + s) * 64 + c];
    // q at last timestep only
    float q = bin[c];
#pragma unroll 8
    for (int k = 0; k < 64; ++k) q += qT[k * 64 + c] * rl(xr[15], k);
    float bk = bin[64 + c], bv = bin[128 + c];
    float vr[16], sr[16];
#pragma unroll
    for (int t = 0; t < 16; ++t) {
      float kk = bk, vv = bv;
#pragma unroll 8
      for (int k = 0; k < 64; ++k) {
        float a = rl(xr[t], k);
        float2 w = *(const float2*)&kvT[(k * 64 + c) * 2];
        kk += w.x * a;
        vv += w.y * a;
      }
      vr[t] = vv;
      float p = q * kk;
      p += __shfl_xor(p, 1);
      p += __shfl_xor(p, 2);
      p += __shfl_xor(p, 4);
      p += __shfl_xor(p, 8);
      sr[t] = p * 0.25f;  // 1/sqrt(HD=16)
    }
    float mx = sr[0];
#pragma unroll
    for (int t = 1; t < 16; ++t) mx = fmaxf(mx, sr[t]);
    float sum = 0.f;
#pragma unroll
    for (int t = 0; t < 16; ++t) { sr[t] = __expf(sr[t] - mx); sum += sr[t]; }
    float inv = 1.f / sum;
    float o = 0.f;
#pragma unroll
    for (int t = 0; t < 16; ++t) o += sr[t] * vr[t];
    o *= inv;
    // out projection
    float fin = bout[c];
#pragma unroll 8
    for (int k = 0; k < 64; ++k) fin += oT[k * 64 + c] * rl(o, k);
    // MLP head
    float z1a = pb1[c], z1b = pb1[64 + c];
#pragma unroll 8
    for (int k = 0; k < 64; ++k) {
      float a = rl(fin, k);
      z1a += w1T[k * 128 + c] * a;
      z1b += w1T[k * 128 + 64 + c] * a;
    }
    z1a = fmaxf(z1a, 0.f);
    z1b = fmaxf(z1b, 0.f);
    float z2 = pb2[c];
#pragma unroll 8
    for (int k = 0; k < 64; ++k) z2 += w2T[k * 64 + c] * rl(z1a, k);
#pragma unroll 8
    for (int k = 0; k < 64; ++k) z2 += w2T[(64 + k) * 64 + c] * rl(z1b, k);
    z2 = fmaxf(z2, 0.f);
    float lg = 0.f;
#pragma unroll 8
    for (int k = 0; k < 64; ++k) lg += w3T[k * 16 + (c & 15)] * rl(z2, k);
    if (c < 13) out[(size_t)s * kNC + c] = lg + pb3[c];
  }
}

// ---------------------------------------------------------------------------
extern "C" void kernel_launch(void* const* d_in, const int* in_sizes, int n_in,
                              void* d_out, int out_size, void* d_ws, size_t ws_size,
                              hipStream_t stream) {
  const float* nf    = (const float*)d_in[0];
  const int*   ei    = (const int*)d_in[1];
  const float* sc_w1 = (const float*)d_in[2];
  const float* sc_b1 = (const float*)d_in[3];
  const float* sc_w2 = (const float*)d_in[4];
  const float* sc_b2 = (const float*)d_in[5];
  const float* wih0  = (const float*)d_in[6];
  const float* whh0  = (const float*)d_in[7];
  const float* bih0  = (const float*)d_in[8];
  const float* bhh0  = (const float*)d_in[9];
  const float* wih1  = (const float*)d_in[10];
  const float* whh1  = (const float*)d_in[11];
  const float* bih1  = (const float*)d_in[12];
  const float* bhh1  = (const float*)d_in[13];
  const float* win   = (const float*)d_in[14];
  const float* bin   = (const float*)d_in[15];
  const float* wout  = (const float*)d_in[16];
  const float* bout  = (const float*)d_in[17];
  const float* pw1   = (const float*)d_in[18];
  const float* pb1   = (const float*)d_in[19];
  const float* pw2   = (const float*)d_in[20];
  const float* pb2   = (const float*)d_in[21];
  const float* pw3   = (const float*)d_in[22];
  const float* pb3   = (const float*)d_in[23];
  float* out = (float*)d_out;

  const size_t NB = (size_t)kT * kBN * 64;  // 16,777,216 floats per buffer
  float* A  = (float*)d_ws;   // conv output h
  float* Bb = A + NB;         // ssum, later LSTM ping buffer
  float* C  = Bb + NB;        // x after aggregation, LSTM pong buffer
  int* cnt  = (int*)(C + NB);

  hipMemsetAsync(Bb, 0, NB * sizeof(float), stream);
  hipMemsetAsync(cnt, 0, (size_t)kT * kN * sizeof(int), stream);

  conv_kernel<<<65536, 256, 0, stream>>>(nf, sc_w1, sc_b1, sc_w2, sc_b2, A);
  scatter_kernel<<<131072, 256, 0, stream>>>(A, ei, Bb, cnt);
  combine_kernel<<<16384, 256, 0, stream>>>(A, Bb, cnt, C);
  lstm_kernel<<<256, 1024, 0, stream>>>(C, Bb, wih0, whh0, bih0, bhh0);
  lstm_kernel<<<256, 1024, 0, stream>>>(Bb, C, wih1, whh1, bih1, bhh1);
  head_kernel<<<256, 1024, 0, stream>>>(C, win, bin, wout, bout,
                                        pw1, pb1, pw2, pb2, pw3, pb3, out);
}

// Round 2
// 1124.085 us; speedup vs baseline: 1.6911x; 1.6911x over previous
//
#include <hip/hip_runtime.h>

// Problem constants
constexpr int kB  = 4;
constexpr int kT  = 16;
constexpr int kN  = 4096;
constexpr int kBN = kB * kN;      // 16384
constexpr int kE  = 32768;
constexpr int kNC = 13;

__device__ __forceinline__ float rl(float v, int l) {
  return __int_as_float(__builtin_amdgcn_readlane(__float_as_int(v), l));
}
__device__ __forceinline__ float sigm(float x) { return 1.f / (1.f + __expf(-x)); }
__device__ __forceinline__ float tanh_(float x) {
  float e = __expf(2.f * x);
  return 1.f - 2.f / (e + 1.f);
}

// ---------------------------------------------------------------------------
// Stage 1: per-node 2-layer MLP (8 -> 64 relu -> 64), thread-per-node.
// Weights are read with wave-uniform indices -> scalar loads (SGPR operand
// in v_fma), no LDS. h written in layout (t, b*N+n, 64).
// ---------------------------------------------------------------------------
__global__ __launch_bounds__(256) void conv_kernel(
    const float* __restrict__ nf, const float* __restrict__ w1,
    const float* __restrict__ b1, const float* __restrict__ w2,
    const float* __restrict__ b2, float* __restrict__ hout) {
  int node = blockIdx.x * 256 + threadIdx.x;   // flat (b,t,n), 262144 total
  int b = node >> 16;
  int t = (node >> 12) & 15;
  int n = node & 4095;
  const float4* src = (const float4*)(nf + (size_t)node * 8);
  float4 x0 = src[0], x1 = src[1];
  float x[8] = {x0.x, x0.y, x0.z, x0.w, x1.x, x1.y, x1.z, x1.w};
  float h1[64];
#pragma unroll
  for (int h = 0; h < 64; ++h) {
    float a = b1[h];
#pragma unroll
    for (int f = 0; f < 8; ++f) a += w1[h * 8 + f] * x[f];
    h1[h] = fmaxf(a, 0.f);
  }
  float* dst = hout + ((size_t)t * kBN + b * kN + n) * 64;
#pragma unroll 1
  for (int g = 0; g < 64; g += 4) {
    float4 acc = {b2[g], b2[g + 1], b2[g + 2], b2[g + 3]};
#pragma unroll
    for (int h = 0; h < 64; ++h) {
      float hh = h1[h];
      acc.x += w2[(g + 0) * 64 + h] * hh;
      acc.y += w2[(g + 1) * 64 + h] * hh;
      acc.z += w2[(g + 2) * 64 + h] * hh;
      acc.w += w2[(g + 3) * 64 + h] * hh;
    }
    *(float4*)(dst + g) = acc;
  }
}

// ---------------------------------------------------------------------------
// Stage 2a: per-(t,dst) edge count (int atomics only)
// ---------------------------------------------------------------------------
__global__ __launch_bounds__(256) void count_kernel(
    const int* __restrict__ ei, int* __restrict__ cnt) {
  int i = blockIdx.x * 256 + threadIdx.x;   // over T*E
  int t = i >> 15, e = i & (kE - 1);
  int dst = ei[t * 2 * kE + kE + e];
  atomicAdd(&cnt[t * kN + dst], 1);
}

// ---------------------------------------------------------------------------
// Stage 2b: per-t exclusive scan over 4096 counts -> offsets + cursor copy.
// one block per t; 1024 threads x 4 values each; Hillis-Steele in LDS.
// ---------------------------------------------------------------------------
__global__ __launch_bounds__(1024) void scan_kernel(
    const int* __restrict__ cnt, int* __restrict__ off, int* __restrict__ cur) {
  __shared__ int sdata[1024];
  int t = blockIdx.x;
  int tid = threadIdx.x;
  const int* c = cnt + t * kN;
  int v0 = c[tid * 4], v1 = c[tid * 4 + 1], v2 = c[tid * 4 + 2], v3 = c[tid * 4 + 3];
  int s = v0 + v1 + v2 + v3;
  sdata[tid] = s;
  __syncthreads();
  for (int d = 1; d < 1024; d <<= 1) {
    int add = (tid >= d) ? sdata[tid - d] : 0;
    __syncthreads();
    sdata[tid] += add;
    __syncthreads();
  }
  int base = sdata[tid] - s;   // exclusive prefix of this thread's chunk
  int o = t * kN + tid * 4;
  off[o] = base;            cur[o] = base;
  off[o + 1] = base + v0;   cur[o + 1] = base + v0;
  off[o + 2] = base + v0 + v1;        cur[o + 2] = base + v0 + v1;
  off[o + 3] = base + v0 + v1 + v2;   cur[o + 3] = base + v0 + v1 + v2;
}

// ---------------------------------------------------------------------------
// Stage 2c: CSR placement — csr[t*E + pos] = src
// ---------------------------------------------------------------------------
__global__ __launch_bounds__(256) void place_kernel(
    const int* __restrict__ ei, int* __restrict__ cur, int* __restrict__ csr) {
  int i = blockIdx.x * 256 + threadIdx.x;
  int t = i >> 15, e = i & (kE - 1);
  int src = ei[t * 2 * kE + e];
  int dst = ei[t * 2 * kE + kE + e];
  int pos = atomicAdd(&cur[t * kN + dst], 1);
  csr[t * kE + pos] = src;
}

// ---------------------------------------------------------------------------
// Stage 2d: gather + combine. wave per (t,dst); lane = channel.
// x = cnt>0 ? (h + mean)*0.5 : h, for all 4 batches.
// ---------------------------------------------------------------------------
__global__ __launch_bounds__(256) void gather_kernel(
    const float* __restrict__ h, const int* __restrict__ csr,
    const int* __restrict__ off, const int* __restrict__ cnt,
    float* __restrict__ x) {
  int g = blockIdx.x * 4 + (threadIdx.x >> 6);   // 0 .. T*N-1
  int t = g >> 12, d = g & (kN - 1);
  int lane = threadIdx.x & 63;
  int o = off[t * kN + d];
  int c = cnt[t * kN + d];
  const float* hb = h + (size_t)t * kBN * 64;
  const int* cs = csr + t * kE + o;
  float s0 = 0.f, s1 = 0.f, s2 = 0.f, s3 = 0.f;
  for (int j = 0; j < c; ++j) {
    int srcn = cs[j];
    s0 += hb[((size_t)0 * kN + srcn) * 64 + lane];
    s1 += hb[((size_t)1 * kN + srcn) * 64 + lane];
    s2 += hb[((size_t)2 * kN + srcn) * 64 + lane];
    s3 += hb[((size_t)3 * kN + srcn) * 64 + lane];
  }
  float* xb = x + (size_t)t * kBN * 64;
  float inv = (c > 0) ? 1.f / (float)c : 0.f;
  float sums[4] = {s0, s1, s2, s3};
#pragma unroll
  for (int b = 0; b < 4; ++b) {
    float hv = hb[((size_t)b * kN + d) * 64 + lane];
    float ov = (c > 0) ? (hv + sums[b] * inv) * 0.5f : hv;
    xb[((size_t)b * kN + d) * 64 + lane] = ov;
  }
}

// ---------------------------------------------------------------------------
// Stage 3: one LSTM layer, persistent over t.
// block = 1024 thr = 16 waves; wave = 4 sequences; lane = channel m.
// LDS: wpack[k][m][g] (k<64: w_ih, k>=64: w_hh), 128 KB.
// ---------------------------------------------------------------------------
__global__ __launch_bounds__(1024) void lstm_kernel(
    const float* __restrict__ xin, float* __restrict__ xout,
    const float* __restrict__ wih, const float* __restrict__ whh,
    const float* __restrict__ bih, const float* __restrict__ bhh) {
  __shared__ __align__(16) float wpack[128 * 64 * 4];  // 131072 B
  int tid = threadIdx.x;
  for (int idx = tid; idx < 16384; idx += 1024) {      // 256x64 each
    int j = idx >> 6, k = idx & 63;
    int g = j >> 6, m = j & 63;
    wpack[((k * 64 + m) << 2) + g] = wih[idx];
    wpack[(((k + 64) * 64 + m) << 2) + g] = whh[idx];
  }
  __syncthreads();
  int wave = tid >> 6, m = tid & 63;
  int s0 = blockIdx.x * 64 + wave * 4;
  float bsum[4];
#pragma unroll
  for (int g = 0; g < 4; ++g) bsum[g] = bih[g * 64 + m] + bhh[g * 64 + m];
  float hr[4] = {0.f, 0.f, 0.f, 0.f};
  float cr[4] = {0.f, 0.f, 0.f, 0.f};
  for (int t = 0; t < kT; ++t) {
    const float* xr = xin + ((size_t)t * kBN + s0) * 64 + m;
    float x0 = xr[0], x1 = xr[64], x2 = xr[128], x3 = xr[192];
    float z[4][4];
#pragma unroll
    for (int i = 0; i < 4; ++i)
#pragma unroll
      for (int g = 0; g < 4; ++g) z[i][g] = bsum[g];
#pragma unroll 16
    for (int k = 0; k < 64; ++k) {
      float4 w = *(const float4*)&wpack[(k * 64 + m) << 2];
      float a0 = rl(x0, k), a1 = rl(x1, k), a2 = rl(x2, k), a3 = rl(x3, k);
      z[0][0] += w.x * a0; z[0][1] += w.y * a0; z[0][2] += w.z * a0; z[0][3] += w.w * a0;
      z[1][0] += w.x * a1; z[1][1] += w.y * a1; z[1][2] += w.z * a1; z[1][3] += w.w * a1;
      z[2][0] += w.x * a2; z[2][1] += w.y * a2; z[2][2] += w.z * a2; z[2][3] += w.w * a2;
      z[3][0] += w.x * a3; z[3][1] += w.y * a3; z[3][2] += w.z * a3; z[3][3] += w.w * a3;
    }
#pragma unroll 16
    for (int k = 0; k < 64; ++k) {
      float4 w = *(const float4*)&wpack[((k + 64) * 64 + m) << 2];
      float a0 = rl(hr[0], k), a1 = rl(hr[1], k), a2 = rl(hr[2], k), a3 = rl(hr[3], k);
      z[0][0] += w.x * a0; z[0][1] += w.y * a0; z[0][2] += w.z * a0; z[0][3] += w.w * a0;
      z[1][0] += w.x * a1; z[1][1] += w.y * a1; z[1][2] += w.z * a1; z[1][3] += w.w * a1;
      z[2][0] += w.x * a2; z[2][1] += w.y * a2; z[2][2] += w.z * a2; z[2][3] += w.w * a2;
      z[3][0] += w.x * a3; z[3][1] += w.y * a3; z[3][2] += w.z * a3; z[3][3] += w.w * a3;
    }
    float* yo = xout + ((size_t)t * kBN + s0) * 64 + m;
#pragma unroll
    for (int i = 0; i < 4; ++i) {
      float ig = sigm(z[i][0]);
      float fg = sigm(z[i][1]);
      float gg = tanh_(z[i][2]);
      float og = sigm(z[i][3]);
      cr[i] = fg * cr[i] + ig * gg;
      hr[i] = og * tanh_(cr[i]);
      yo[i * 64] = hr[i];
    }
  }
}

// ---------------------------------------------------------------------------
// Stage 4: attention (last-query only) + out-proj + 3-layer MLP head, fused.
// ---------------------------------------------------------------------------
__global__ __launch_bounds__(1024) void head_kernel(
    const float* __restrict__ x, const float* __restrict__ win,
    const float* __restrict__ bin, const float* __restrict__ wout,
    const float* __restrict__ bout, const float* __restrict__ pw1,
    const float* __restrict__ pb1, const float* __restrict__ pw2,
    const float* __restrict__ pb2, const float* __restrict__ pw3,
    const float* __restrict__ pb3, float* __restrict__ out) {
  __shared__ float qT[64 * 64];                    // [k][c]
  __shared__ __align__(8) float kvT[64 * 64 * 2];  // [k][c][{k,v}]
  __shared__ float oT[64 * 64];                    // [k][c]
  __shared__ float w1T[64 * 128];                  // [k][j]
  __shared__ float w2T[128 * 64];                  // [k][c]
  __shared__ float w3T[64 * 16];                   // [k][c<16]
  int tid = threadIdx.x;
  for (int i = tid; i < 4096; i += 1024) {
    int r = i >> 6, k = i & 63;
    qT[k * 64 + r] = win[r * 64 + k];
    kvT[(k * 64 + r) * 2 + 0] = win[(64 + r) * 64 + k];
    kvT[(k * 64 + r) * 2 + 1] = win[(128 + r) * 64 + k];
    oT[k * 64 + r] = wout[r * 64 + k];
  }
  for (int i = tid; i < 8192; i += 1024) {
    int j = i >> 6, k = i & 63;
    w1T[k * 128 + j] = pw1[i];
  }
  for (int i = tid; i < 8192; i += 1024) {
    int r = i >> 7, k = i & 127;
    w2T[k * 64 + r] = pw2[i];
  }
  for (int i = tid; i < 1024; i += 1024) {
    int k = i >> 4, c = i & 15;
    w3T[i] = (c < 13) ? pw3[c * 64 + k] : 0.f;
  }
  __syncthreads();
  int wave = tid >> 6, c = tid & 63;
  for (int it = 0; it < 4; ++it) {
    int s = blockIdx.x * 64 + wave * 4 + it;
    float xr[16];
#pragma unroll
    for (int t = 0; t < 16; ++t) xr[t] = x[((size_t)t * kBN + s) * 64 + c];
    float q = bin[c];
#pragma unroll 8
    for (int k = 0; k < 64; ++k) q += qT[k * 64 + c] * rl(xr[15], k);
    float bk = bin[64 + c], bv = bin[128 + c];
    float vr[16], sr[16];
#pragma unroll
    for (int t = 0; t < 16; ++t) {
      float kk = bk, vv = bv;
#pragma unroll 8
      for (int k = 0; k < 64; ++k) {
        float a = rl(xr[t], k);
        float2 w = *(const float2*)&kvT[(k * 64 + c) * 2];
        kk += w.x * a;
        vv += w.y * a;
      }
      vr[t] = vv;
      float p = q * kk;
      p += __shfl_xor(p, 1);
      p += __shfl_xor(p, 2);
      p += __shfl_xor(p, 4);
      p += __shfl_xor(p, 8);
      sr[t] = p * 0.25f;  // 1/sqrt(HD=16)
    }
    float mx = sr[0];
#pragma unroll
    for (int t = 1; t < 16; ++t) mx = fmaxf(mx, sr[t]);
    float sum = 0.f;
#pragma unroll
    for (int t = 0; t < 16; ++t) { sr[t] = __expf(sr[t] - mx); sum += sr[t]; }
    float inv = 1.f / sum;
    float o = 0.f;
#pragma unroll
    for (int t = 0; t < 16; ++t) o += sr[t] * vr[t];
    o *= inv;
    float fin = bout[c];
#pragma unroll 8
    for (int k = 0; k < 64; ++k) fin += oT[k * 64 + c] * rl(o, k);
    float z1a = pb1[c], z1b = pb1[64 + c];
#pragma unroll 8
    for (int k = 0; k < 64; ++k) {
      float a = rl(fin, k);
      z1a += w1T[k * 128 + c] * a;
      z1b += w1T[k * 128 + 64 + c] * a;
    }
    z1a = fmaxf(z1a, 0.f);
    z1b = fmaxf(z1b, 0.f);
    float z2 = pb2[c];
#pragma unroll 8
    for (int k = 0; k < 64; ++k) z2 += w2T[k * 64 + c] * rl(z1a, k);
#pragma unroll 8
    for (int k = 0; k < 64; ++k) z2 += w2T[(64 + k) * 64 + c] * rl(z1b, k);
    z2 = fmaxf(z2, 0.f);
    float lg = 0.f;
#pragma unroll 8
    for (int k = 0; k < 64; ++k) lg += w3T[k * 16 + (c & 15)] * rl(z2, k);
    if (c < 13) out[(size_t)s * kNC + c] = lg + pb3[c];
  }
}

// ---------------------------------------------------------------------------
extern "C" void kernel_launch(void* const* d_in, const int* in_sizes, int n_in,
                              void* d_out, int out_size, void* d_ws, size_t ws_size,
                              hipStream_t stream) {
  const float* nf    = (const float*)d_in[0];
  const int*   ei    = (const int*)d_in[1];
  const float* sc_w1 = (const float*)d_in[2];
  const float* sc_b1 = (const float*)d_in[3];
  const float* sc_w2 = (const float*)d_in[4];
  const float* sc_b2 = (const float*)d_in[5];
  const float* wih0  = (const float*)d_in[6];
  const float* whh0  = (const float*)d_in[7];
  const float* bih0  = (const float*)d_in[8];
  const float* bhh0  = (const float*)d_in[9];
  const float* wih1  = (const float*)d_in[10];
  const float* whh1  = (const float*)d_in[11];
  const float* bih1  = (const float*)d_in[12];
  const float* bhh1  = (const float*)d_in[13];
  const float* win   = (const float*)d_in[14];
  const float* bin   = (const float*)d_in[15];
  const float* wout  = (const float*)d_in[16];
  const float* bout  = (const float*)d_in[17];
  const float* pw1   = (const float*)d_in[18];
  const float* pb1   = (const float*)d_in[19];
  const float* pw2   = (const float*)d_in[20];
  const float* pb2   = (const float*)d_in[21];
  const float* pw3   = (const float*)d_in[22];
  const float* pb3   = (const float*)d_in[23];
  float* out = (float*)d_out;

  const size_t NB = (size_t)kT * kBN * 64;  // 16,777,216 floats per buffer
  float* A = (float*)d_ws;   // conv output h; later LSTM ping buffer
  float* C = A + NB;         // x after aggregation; LSTM pong buffer
  int* cnt = (int*)(C + NB);           // T*N
  int* off = cnt + kT * kN;            // T*N
  int* cur = off + kT * kN;            // T*N
  int* csr = cur + kT * kN;            // T*E

  hipMemsetAsync(cnt, 0, (size_t)kT * kN * sizeof(int), stream);

  conv_kernel<<<1024, 256, 0, stream>>>(nf, sc_w1, sc_b1, sc_w2, sc_b2, A);
  count_kernel<<<2048, 256, 0, stream>>>(ei, cnt);
  scan_kernel<<<16, 1024, 0, stream>>>(cnt, off, cur);
  place_kernel<<<2048, 256, 0, stream>>>(ei, cur, csr);
  gather_kernel<<<16384, 256, 0, stream>>>(A, csr, off, cnt, C);
  lstm_kernel<<<256, 1024, 0, stream>>>(C, A, wih0, whh0, bih0, bhh0);
  lstm_kernel<<<256, 1024, 0, stream>>>(A, C, wih1, whh1, bih1, bhh1);
  head_kernel<<<256, 1024, 0, stream>>>(C, win, bin, wout, bout,
                                        pw1, pb1, pw2, pb2, pw3, pb3, out);
}

// Round 3
// 725.959 us; speedup vs baseline: 2.6185x; 1.5484x over previous
//
#include <hip/hip_runtime.h>

// Problem constants
constexpr int kB  = 4;
constexpr int kT  = 16;
constexpr int kN  = 4096;
constexpr int kBN = kB * kN;      // 16384
constexpr int kE  = 32768;
constexpr int kNC = 13;

typedef _Float16 f16x8 __attribute__((ext_vector_type(8)));
typedef float f32x4 __attribute__((ext_vector_type(4)));

__device__ __forceinline__ float rl(float v, int l) {
  return __int_as_float(__builtin_amdgcn_readlane(__float_as_int(v), l));
}
__device__ __forceinline__ float sigm(float x) { return 1.f / (1.f + __expf(-x)); }
__device__ __forceinline__ float tanh_(float x) {
  float e = __expf(2.f * x);
  return 1.f - 2.f / (e + 1.f);
}

// ---------------------------------------------------------------------------
// Stage 1: per-node 2-layer MLP (8 -> 64 relu -> 64), thread-per-node.
// ---------------------------------------------------------------------------
__global__ __launch_bounds__(256) void conv_kernel(
    const float* __restrict__ nf, const float* __restrict__ w1,
    const float* __restrict__ b1, const float* __restrict__ w2,
    const float* __restrict__ b2, float* __restrict__ hout) {
  int node = blockIdx.x * 256 + threadIdx.x;   // flat (b,t,n), 262144 total
  int b = node >> 16;
  int t = (node >> 12) & 15;
  int n = node & 4095;
  const float4* src = (const float4*)(nf + (size_t)node * 8);
  float4 x0 = src[0], x1 = src[1];
  float x[8] = {x0.x, x0.y, x0.z, x0.w, x1.x, x1.y, x1.z, x1.w};
  float h1[64];
#pragma unroll
  for (int h = 0; h < 64; ++h) {
    float a = b1[h];
#pragma unroll
    for (int f = 0; f < 8; ++f) a += w1[h * 8 + f] * x[f];
    h1[h] = fmaxf(a, 0.f);
  }
  float* dst = hout + ((size_t)t * kBN + b * kN + n) * 64;
#pragma unroll 1
  for (int g = 0; g < 64; g += 4) {
    float4 acc = {b2[g], b2[g + 1], b2[g + 2], b2[g + 3]};
#pragma unroll
    for (int h = 0; h < 64; ++h) {
      float hh = h1[h];
      acc.x += w2[(g + 0) * 64 + h] * hh;
      acc.y += w2[(g + 1) * 64 + h] * hh;
      acc.z += w2[(g + 2) * 64 + h] * hh;
      acc.w += w2[(g + 3) * 64 + h] * hh;
    }
    *(float4*)(dst + g) = acc;
  }
}

// ---------------------------------------------------------------------------
// Stage 2a: per-(t,dst) edge count (int atomics only)
// ---------------------------------------------------------------------------
__global__ __launch_bounds__(256) void count_kernel(
    const int* __restrict__ ei, int* __restrict__ cnt) {
  int i = blockIdx.x * 256 + threadIdx.x;   // over T*E
  int t = i >> 15, e = i & (kE - 1);
  int dst = ei[t * 2 * kE + kE + e];
  atomicAdd(&cnt[t * kN + dst], 1);
}

// ---------------------------------------------------------------------------
// Stage 2b: per-t exclusive scan over 4096 counts -> offsets + cursor copy.
// ---------------------------------------------------------------------------
__global__ __launch_bounds__(1024) void scan_kernel(
    const int* __restrict__ cnt, int* __restrict__ off, int* __restrict__ cur) {
  __shared__ int sdata[1024];
  int t = blockIdx.x;
  int tid = threadIdx.x;
  const int* c = cnt + t * kN;
  int v0 = c[tid * 4], v1 = c[tid * 4 + 1], v2 = c[tid * 4 + 2], v3 = c[tid * 4 + 3];
  int s = v0 + v1 + v2 + v3;
  sdata[tid] = s;
  __syncthreads();
  for (int d = 1; d < 1024; d <<= 1) {
    int add = (tid >= d) ? sdata[tid - d] : 0;
    __syncthreads();
    sdata[tid] += add;
    __syncthreads();
  }
  int base = sdata[tid] - s;
  int o = t * kN + tid * 4;
  off[o] = base;            cur[o] = base;
  off[o + 1] = base + v0;   cur[o + 1] = base + v0;
  off[o + 2] = base + v0 + v1;        cur[o + 2] = base + v0 + v1;
  off[o + 3] = base + v0 + v1 + v2;   cur[o + 3] = base + v0 + v1 + v2;
}

// ---------------------------------------------------------------------------
// Stage 2c: CSR placement — csr[t*E + pos] = src
// ---------------------------------------------------------------------------
__global__ __launch_bounds__(256) void place_kernel(
    const int* __restrict__ ei, int* __restrict__ cur, int* __restrict__ csr) {
  int i = blockIdx.x * 256 + threadIdx.x;
  int t = i >> 15, e = i & (kE - 1);
  int src = ei[t * 2 * kE + e];
  int dst = ei[t * 2 * kE + kE + e];
  int pos = atomicAdd(&cur[t * kN + dst], 1);
  csr[t * kE + pos] = src;
}

// ---------------------------------------------------------------------------
// Stage 2d: gather + combine. wave per (t,dst); lane = (batch, channel-quad).
// One float4 per edge per lane covers all 4 batches in one wave-instruction.
// ---------------------------------------------------------------------------
__global__ __launch_bounds__(256) void gather_kernel(
    const float* __restrict__ h, const int* __restrict__ csr,
    const int* __restrict__ off, const int* __restrict__ cnt,
    float* __restrict__ x) {
  int wv = blockIdx.x * 4 + (threadIdx.x >> 6);   // 0 .. T*N-1
  int t = wv >> 12, d = wv & (kN - 1);
  int lane = threadIdx.x & 63;
  int b = lane >> 4, cq = lane & 15;              // batch, channel quad
  int o = off[t * kN + d];
  int c = cnt[t * kN + d];
  const float* hb = h + (size_t)t * kBN * 64;
  const int* cs = csr + t * kE + o;
  float sx = 0.f, sy = 0.f, sz = 0.f, sw = 0.f;
  size_t bbase = (size_t)b * kN;
  int j = 0;
  for (; j + 4 <= c; j += 4) {
    int i0 = cs[j], i1 = cs[j + 1], i2 = cs[j + 2], i3 = cs[j + 3];
    float4 v0 = *(const float4*)&hb[(bbase + i0) * 64 + cq * 4];
    float4 v1 = *(const float4*)&hb[(bbase + i1) * 64 + cq * 4];
    float4 v2 = *(const float4*)&hb[(bbase + i2) * 64 + cq * 4];
    float4 v3 = *(const float4*)&hb[(bbase + i3) * 64 + cq * 4];
    sx += v0.x + v1.x + v2.x + v3.x;
    sy += v0.y + v1.y + v2.y + v3.y;
    sz += v0.z + v1.z + v2.z + v3.z;
    sw += v0.w + v1.w + v2.w + v3.w;
  }
  for (; j < c; ++j) {
    int i0 = cs[j];
    float4 v0 = *(const float4*)&hb[(bbase + i0) * 64 + cq * 4];
    sx += v0.x; sy += v0.y; sz += v0.z; sw += v0.w;
  }
  float4 hv = *(const float4*)&hb[(bbase + d) * 64 + cq * 4];
  float4 ov;
  if (c > 0) {
    float inv = 1.f / (float)c;
    ov.x = (hv.x + sx * inv) * 0.5f;
    ov.y = (hv.y + sy * inv) * 0.5f;
    ov.z = (hv.z + sz * inv) * 0.5f;
    ov.w = (hv.w + sw * inv) * 0.5f;
  } else {
    ov = hv;
  }
  *(float4*)&x[(size_t)t * kBN * 64 + (bbase + d) * 64 + cq * 4] = ov;
}

// ---------------------------------------------------------------------------
// Stage 3: one LSTM layer via split-precision fp16 MFMA (hi/lo, 3 terms:
// Ah*Bh + Ah*Bl + Al*Bh ~= fp32). Block = 256 thr (4 waves) = 64 seqs.
// Wave w owns channel block [16w,16w+16) across all 4 gates (N-tiles g*4+w),
// all 4 M-tiles. Weights pre-split hi/lo into LDS in B-fragment order
// (128 KB); h exchanged per-t via LDS in A-fragment order (16 KB).
// Fragment maps (m89/m120-verified): A[m=lane&15][k=(lane>>4)*8+j],
// B[k=(lane>>4)*8+j][n=lane&15], D[row=(lane>>4)*4+r][col=lane&15].
// ---------------------------------------------------------------------------
__global__ __launch_bounds__(256, 1) void lstm_kernel(
    const float* __restrict__ xin, float* __restrict__ xout,
    const float* __restrict__ wih, const float* __restrict__ whh,
    const float* __restrict__ bih, const float* __restrict__ bhh) {
  // [mat][hl][nt][ks][lane*8+j]  (nt = N-tile 0..15, ks = k-step 0..1)
  __shared__ __align__(16) _Float16 wfrag[2][2][16][2][512];  // 131072 B
  // [Mt][ks][hl][lane*8+j]
  __shared__ __align__(16) _Float16 hfrag[4][2][2][512];      // 16384 B

  int tid = threadIdx.x;
  // --- stage W as hi/lo fragments (once) ---
  for (int idx = tid; idx < 2 * 256 * 16; idx += 256) {  // float4 units
    int mat = idx >> 12;
    int r = (idx >> 4) & 255;   // output row n (gate-channel)
    int k4 = idx & 15;
    const float* W = mat ? whh : wih;
    float4 v = *(const float4*)&W[r * 64 + k4 * 4];
    int k = k4 * 4;
    int nt = r >> 4, i = r & 15, ks = k >> 5, q = (k >> 3) & 3, j0 = k & 7;
    int lane = q * 16 + i;
    _Float16* dh = &wfrag[mat][0][nt][ks][lane * 8 + j0];
    _Float16* dl = &wfrag[mat][1][nt][ks][lane * 8 + j0];
    float vv[4] = {v.x, v.y, v.z, v.w};
#pragma unroll
    for (int u = 0; u < 4; ++u) {
      _Float16 hh = (_Float16)vv[u];
      dh[u] = hh;
      dl[u] = (_Float16)(vv[u] - (float)hh);
    }
  }

  int w = tid >> 6, lane = tid & 63;
  int q = lane >> 4, i = lane & 15;
  int s0 = blockIdx.x * 64;
  float bias4[4];
#pragma unroll
  for (int g = 0; g < 4; ++g) {
    int col = g * 64 + w * 16 + i;
    bias4[g] = bih[col] + bhh[col];
  }
  float cstate[4][4];
#pragma unroll
  for (int Mt = 0; Mt < 4; ++Mt)
#pragma unroll
    for (int r = 0; r < 4; ++r) cstate[Mt][r] = 0.f;

  // h-frag write coordinates for this lane's channel
  int ch = w * 16 + i;
  int ks2 = ch >> 5, q2 = (ch >> 3) & 3, j2 = ch & 7;

  __syncthreads();

  for (int t = 0; t < kT; ++t) {
    // ---- load x fragments from global (hi/lo split) ----
    f16x8 xa[4][2][2];
#pragma unroll
    for (int Mt = 0; Mt < 4; ++Mt)
#pragma unroll
      for (int ks = 0; ks < 2; ++ks) {
        const float* p = xin + ((size_t)t * kBN + s0 + Mt * 16 + i) * 64 + ks * 32 + q * 8;
        float4 u0 = *(const float4*)p;
        float4 u1 = *(const float4*)(p + 4);
        float vv[8] = {u0.x, u0.y, u0.z, u0.w, u1.x, u1.y, u1.z, u1.w};
        f16x8 hi, lo;
#pragma unroll
        for (int j = 0; j < 8; ++j) {
          _Float16 hj = (_Float16)vv[j];
          hi[j] = hj;
          lo[j] = (_Float16)(vv[j] - (float)hj);
        }
        xa[Mt][ks][0] = hi;
        xa[Mt][ks][1] = lo;
      }
    // ---- load h fragments from LDS (gen t-1) ----
    f16x8 ha[4][2][2];
    if (t > 0) {
#pragma unroll
      for (int Mt = 0; Mt < 4; ++Mt)
#pragma unroll
        for (int ks = 0; ks < 2; ++ks) {
          ha[Mt][ks][0] = *(const f16x8*)&hfrag[Mt][ks][0][lane * 8];
          ha[Mt][ks][1] = *(const f16x8*)&hfrag[Mt][ks][1][lane * 8];
        }
    } else {
#pragma unroll
      for (int Mt = 0; Mt < 4; ++Mt)
#pragma unroll
        for (int ks = 0; ks < 2; ++ks) {
          ha[Mt][ks][0] = (f16x8)0;
          ha[Mt][ks][1] = (f16x8)0;
        }
    }
    __syncthreads();   // all waves done reading hfrag(t-1)

    // ---- MFMA: z = bias + x@Wih^T + h@Whh^T, fp16x3 ----
    f32x4 acc[4][4];   // [Mt][gate]
#pragma unroll
    for (int Mt = 0; Mt < 4; ++Mt)
#pragma unroll
      for (int g = 0; g < 4; ++g) {
        acc[Mt][g][0] = bias4[g]; acc[Mt][g][1] = bias4[g];
        acc[Mt][g][2] = bias4[g]; acc[Mt][g][3] = bias4[g];
      }
#pragma unroll
    for (int g = 0; g < 4; ++g) {
      int nt = g * 4 + w;
      f16x8 bf[2][2][2];   // [mat][ks][hl]
#pragma unroll
      for (int mat = 0; mat < 2; ++mat)
#pragma unroll
        for (int ks = 0; ks < 2; ++ks) {
          bf[mat][ks][0] = *(const f16x8*)&wfrag[mat][0][nt][ks][lane * 8];
          bf[mat][ks][1] = *(const f16x8*)&wfrag[mat][1][nt][ks][lane * 8];
        }
#pragma unroll
      for (int Mt = 0; Mt < 4; ++Mt) {
        f32x4 a = acc[Mt][g];
#pragma unroll
        for (int ks = 0; ks < 2; ++ks) {
          a = __builtin_amdgcn_mfma_f32_16x16x32_f16(xa[Mt][ks][0], bf[0][ks][0], a, 0, 0, 0);
          a = __builtin_amdgcn_mfma_f32_16x16x32_f16(xa[Mt][ks][0], bf[0][ks][1], a, 0, 0, 0);
          a = __builtin_amdgcn_mfma_f32_16x16x32_f16(xa[Mt][ks][1], bf[0][ks][0], a, 0, 0, 0);
          a = __builtin_amdgcn_mfma_f32_16x16x32_f16(ha[Mt][ks][0], bf[1][ks][0], a, 0, 0, 0);
          a = __builtin_amdgcn_mfma_f32_16x16x32_f16(ha[Mt][ks][0], bf[1][ks][1], a, 0, 0, 0);
          a = __builtin_amdgcn_mfma_f32_16x16x32_f16(ha[Mt][ks][1], bf[1][ks][0], a, 0, 0, 0);
        }
        acc[Mt][g] = a;
      }
    }

    // ---- gates + state update + write h (global + LDS frags) ----
#pragma unroll
    for (int Mt = 0; Mt < 4; ++Mt)
#pragma unroll
      for (int r = 0; r < 4; ++r) {
        float zi = acc[Mt][0][r], zf = acc[Mt][1][r];
        float zg = acc[Mt][2][r], zo = acc[Mt][3][r];
        float ig = sigm(zi), fg = sigm(zf), gg = tanh_(zg), og = sigm(zo);
        float c = fg * cstate[Mt][r] + ig * gg;
        cstate[Mt][r] = c;
        float hv = og * tanh_(c);
        int row = q * 4 + r;
        xout[((size_t)t * kBN + s0 + Mt * 16 + row) * 64 + ch] = hv;
        _Float16 hh = (_Float16)hv;
        int lane2 = q2 * 16 + row;
        hfrag[Mt][ks2][0][lane2 * 8 + j2] = hh;
        hfrag[Mt][ks2][1][lane2 * 8 + j2] = (_Float16)(hv - (float)hh);
      }
    __syncthreads();   // hfrag(t) visible before t+1 reads
  }
}

// ---------------------------------------------------------------------------
// Stage 4: attention (last-query only) + out-proj + 3-layer MLP head, fused.
// ---------------------------------------------------------------------------
__global__ __launch_bounds__(1024) void head_kernel(
    const float* __restrict__ x, const float* __restrict__ win,
    const float* __restrict__ bin, const float* __restrict__ wout,
    const float* __restrict__ bout, const float* __restrict__ pw1,
    const float* __restrict__ pb1, const float* __restrict__ pw2,
    const float* __restrict__ pb2, const float* __restrict__ pw3,
    const float* __restrict__ pb3, float* __restrict__ out) {
  __shared__ float qT[64 * 64];                    // [k][c]
  __shared__ __align__(8) float kvT[64 * 64 * 2];  // [k][c][{k,v}]
  __shared__ float oT[64 * 64];                    // [k][c]
  __shared__ float w1T[64 * 128];                  // [k][j]
  __shared__ float w2T[128 * 64];                  // [k][c]
  __shared__ float w3T[64 * 16];                   // [k][c<16]
  int tid = threadIdx.x;
  for (int i = tid; i < 4096; i += 1024) {
    int r = i >> 6, k = i & 63;
    qT[k * 64 + r] = win[r * 64 + k];
    kvT[(k * 64 + r) * 2 + 0] = win[(64 + r) * 64 + k];
    kvT[(k * 64 + r) * 2 + 1] = win[(128 + r) * 64 + k];
    oT[k * 64 + r] = wout[r * 64 + k];
  }
  for (int i = tid; i < 8192; i += 1024) {
    int j = i >> 6, k = i & 63;
    w1T[k * 128 + j] = pw1[i];
  }
  for (int i = tid; i < 8192; i += 1024) {
    int r = i >> 7, k = i & 127;
    w2T[k * 64 + r] = pw2[i];
  }
  for (int i = tid; i < 1024; i += 1024) {
    int k = i >> 4, c = i & 15;
    w3T[i] = (c < 13) ? pw3[c * 64 + k] : 0.f;
  }
  __syncthreads();
  int wave = tid >> 6, c = tid & 63;
  for (int it = 0; it < 4; ++it) {
    int s = blockIdx.x * 64 + wave * 4 + it;
    float xr[16];
#pragma unroll
    for (int t = 0; t < 16; ++t) xr[t] = x[((size_t)t * kBN + s) * 64 + c];
    float q = bin[c];
#pragma unroll 8
    for (int k = 0; k < 64; ++k) q += qT[k * 64 + c] * rl(xr[15], k);
    float bk = bin[64 + c], bv = bin[128 + c];
    float vr[16], sr[16];
#pragma unroll
    for (int t = 0; t < 16; ++t) {
      float kk = bk, vv = bv;
#pragma unroll 8
      for (int k = 0; k < 64; ++k) {
        float a = rl(xr[t], k);
        float2 w = *(const float2*)&kvT[(k * 64 + c) * 2];
        kk += w.x * a;
        vv += w.y * a;
      }
      vr[t] = vv;
      float p = q * kk;
      p += __shfl_xor(p, 1);
      p += __shfl_xor(p, 2);
      p += __shfl_xor(p, 4);
      p += __shfl_xor(p, 8);
      sr[t] = p * 0.25f;  // 1/sqrt(HD=16)
    }
    float mx = sr[0];
#pragma unroll
    for (int t = 1; t < 16; ++t) mx = fmaxf(mx, sr[t]);
    float sum = 0.f;
#pragma unroll
    for (int t = 0; t < 16; ++t) { sr[t] = __expf(sr[t] - mx); sum += sr[t]; }
    float inv = 1.f / sum;
    float o = 0.f;
#pragma unroll
    for (int t = 0; t < 16; ++t) o += sr[t] * vr[t];
    o *= inv;
    float fin = bout[c];
#pragma unroll 8
    for (int k = 0; k < 64; ++k) fin += oT[k * 64 + c] * rl(o, k);
    float z1a = pb1[c], z1b = pb1[64 + c];
#pragma unroll 8
    for (int k = 0; k < 64; ++k) {
      float a = rl(fin, k);
      z1a += w1T[k * 128 + c] * a;
      z1b += w1T[k * 128 + 64 + c] * a;
    }
    z1a = fmaxf(z1a, 0.f);
    z1b = fmaxf(z1b, 0.f);
    float z2 = pb2[c];
#pragma unroll 8
    for (int k = 0; k < 64; ++k) z2 += w2T[k * 64 + c] * rl(z1a, k);
#pragma unroll 8
    for (int k = 0; k < 64; ++k) z2 += w2T[(64 + k) * 64 + c] * rl(z1b, k);
    z2 = fmaxf(z2, 0.f);
    float lg = 0.f;
#pragma unroll 8
    for (int k = 0; k < 64; ++k) lg += w3T[k * 16 + (c & 15)] * rl(z2, k);
    if (c < 13) out[(size_t)s * kNC + c] = lg + pb3[c];
  }
}

// ---------------------------------------------------------------------------
extern "C" void kernel_launch(void* const* d_in, const int* in_sizes, int n_in,
                              void* d_out, int out_size, void* d_ws, size_t ws_size,
                              hipStream_t stream) {
  const float* nf    = (const float*)d_in[0];
  const int*   ei    = (const int*)d_in[1];
  const float* sc_w1 = (const float*)d_in[2];
  const float* sc_b1 = (const float*)d_in[3];
  const float* sc_w2 = (const float*)d_in[4];
  const float* sc_b2 = (const float*)d_in[5];
  const float* wih0  = (const float*)d_in[6];
  const float* whh0  = (const float*)d_in[7];
  const float* bih0  = (const float*)d_in[8];
  const float* bhh0  = (const float*)d_in[9];
  const float* wih1  = (const float*)d_in[10];
  const float* whh1  = (const float*)d_in[11];
  const float* bih1  = (const float*)d_in[12];
  const float* bhh1  = (const float*)d_in[13];
  const float* win   = (const float*)d_in[14];
  const float* bin   = (const float*)d_in[15];
  const float* wout  = (const float*)d_in[16];
  const float* bout  = (const float*)d_in[17];
  const float* pw1   = (const float*)d_in[18];
  const float* pb1   = (const float*)d_in[19];
  const float* pw2   = (const float*)d_in[20];
  const float* pb2   = (const float*)d_in[21];
  const float* pw3   = (const float*)d_in[22];
  const float* pb3   = (const float*)d_in[23];
  float* out = (float*)d_out;

  const size_t NB = (size_t)kT * kBN * 64;  // 16,777,216 floats per buffer
  float* A = (float*)d_ws;   // conv output h; later LSTM ping buffer
  float* C = A + NB;         // x after aggregation; LSTM pong buffer
  int* cnt = (int*)(C + NB);           // T*N
  int* off = cnt + kT * kN;            // T*N
  int* cur = off + kT * kN;            // T*N
  int* csr = cur + kT * kN;            // T*E

  hipMemsetAsync(cnt, 0, (size_t)kT * kN * sizeof(int), stream);

  conv_kernel<<<1024, 256, 0, stream>>>(nf, sc_w1, sc_b1, sc_w2, sc_b2, A);
  count_kernel<<<2048, 256, 0, stream>>>(ei, cnt);
  scan_kernel<<<16, 1024, 0, stream>>>(cnt, off, cur);
  place_kernel<<<2048, 256, 0, stream>>>(ei, cur, csr);
  gather_kernel<<<16384, 256, 0, stream>>>(A, csr, off, cnt, C);
  lstm_kernel<<<256, 256, 0, stream>>>(C, A, wih0, whh0, bih0, bhh0);
  lstm_kernel<<<256, 256, 0, stream>>>(A, C, wih1, whh1, bih1, bhh1);
  head_kernel<<<256, 1024, 0, stream>>>(C, win, bin, wout, bout,
                                        pw1, pb1, pw2, pb2, pw3, pb3, out);
}

// Round 4
// 592.224 us; speedup vs baseline: 3.2098x; 1.2258x over previous
//
#include <hip/hip_runtime.h>

// Problem constants
constexpr int kB  = 4;
constexpr int kT  = 16;
constexpr int kN  = 4096;
constexpr int kBN = kB * kN;      // 16384
constexpr int kE  = 32768;
constexpr int kNC = 13;

typedef _Float16 f16x8 __attribute__((ext_vector_type(8)));
typedef float f32x4 __attribute__((ext_vector_type(4)));

__device__ __forceinline__ float rl(float v, int l) {
  return __int_as_float(__builtin_amdgcn_readlane(__float_as_int(v), l));
}
__device__ __forceinline__ float sigm(float x) { return 1.f / (1.f + __expf(-x)); }
__device__ __forceinline__ float tanh_(float x) {
  float e = __expf(2.f * x);
  return 1.f - 2.f / (e + 1.f);
}

__device__ __forceinline__ f32x4 mm3(f16x8 ah, f16x8 al, f16x8 bh, f16x8 bl, f32x4 acc) {
  acc = __builtin_amdgcn_mfma_f32_16x16x32_f16(ah, bh, acc, 0, 0, 0);
  acc = __builtin_amdgcn_mfma_f32_16x16x32_f16(ah, bl, acc, 0, 0, 0);
  acc = __builtin_amdgcn_mfma_f32_16x16x32_f16(al, bh, acc, 0, 0, 0);
  return acc;
}

// split 8 consecutive fp32 into hi/lo fp16 A-frag registers
__device__ __forceinline__ void split8(const float* p, f16x8& hi, f16x8& lo) {
  float4 u0 = *(const float4*)p, u1 = *(const float4*)(p + 4);
  float vv[8] = {u0.x, u0.y, u0.z, u0.w, u1.x, u1.y, u1.z, u1.w};
#pragma unroll
  for (int j = 0; j < 8; ++j) {
    _Float16 hj = (_Float16)vv[j];
    hi[j] = hj;
    lo[j] = (_Float16)(vv[j] - (float)hj);
  }
}

// split from transposed LDS activation buffer [col][seq], row stride 68
__device__ __forceinline__ void split8T(const float* base, int kbase, int seq,
                                        f16x8& hi, f16x8& lo) {
  float vv[8];
#pragma unroll
  for (int j = 0; j < 8; ++j) vv[j] = base[(kbase + j) * 68 + seq];
#pragma unroll
  for (int j = 0; j < 8; ++j) {
    _Float16 hj = (_Float16)vv[j];
    hi[j] = hj;
    lo[j] = (_Float16)(vv[j] - (float)hj);
  }
}

// ---------------------------------------------------------------------------
// Stage 1: per-node 2-layer MLP (8 -> 64 relu -> 64), thread-per-node.
// ---------------------------------------------------------------------------
__global__ __launch_bounds__(256) void conv_kernel(
    const float* __restrict__ nf, const float* __restrict__ w1,
    const float* __restrict__ b1, const float* __restrict__ w2,
    const float* __restrict__ b2, float* __restrict__ hout) {
  int node = blockIdx.x * 256 + threadIdx.x;   // flat (b,t,n), 262144 total
  int b = node >> 16;
  int t = (node >> 12) & 15;
  int n = node & 4095;
  const float4* src = (const float4*)(nf + (size_t)node * 8);
  float4 x0 = src[0], x1 = src[1];
  float x[8] = {x0.x, x0.y, x0.z, x0.w, x1.x, x1.y, x1.z, x1.w};
  float h1[64];
#pragma unroll
  for (int h = 0; h < 64; ++h) {
    float a = b1[h];
#pragma unroll
    for (int f = 0; f < 8; ++f) a += w1[h * 8 + f] * x[f];
    h1[h] = fmaxf(a, 0.f);
  }
  float* dst = hout + ((size_t)t * kBN + b * kN + n) * 64;
#pragma unroll 1
  for (int g = 0; g < 64; g += 4) {
    float4 acc = {b2[g], b2[g + 1], b2[g + 2], b2[g + 3]};
#pragma unroll
    for (int h = 0; h < 64; ++h) {
      float hh = h1[h];
      acc.x += w2[(g + 0) * 64 + h] * hh;
      acc.y += w2[(g + 1) * 64 + h] * hh;
      acc.z += w2[(g + 2) * 64 + h] * hh;
      acc.w += w2[(g + 3) * 64 + h] * hh;
    }
    *(float4*)(dst + g) = acc;
  }
}

// ---------------------------------------------------------------------------
// Stage 2a: per-(t,dst) edge count (int atomics only)
// ---------------------------------------------------------------------------
__global__ __launch_bounds__(256) void count_kernel(
    const int* __restrict__ ei, int* __restrict__ cnt) {
  int i = blockIdx.x * 256 + threadIdx.x;   // over T*E
  int t = i >> 15, e = i & (kE - 1);
  int dst = ei[t * 2 * kE + kE + e];
  atomicAdd(&cnt[t * kN + dst], 1);
}

// ---------------------------------------------------------------------------
// Stage 2b: per-t exclusive scan over 4096 counts -> offsets + cursor copy.
// ---------------------------------------------------------------------------
__global__ __launch_bounds__(1024) void scan_kernel(
    const int* __restrict__ cnt, int* __restrict__ off, int* __restrict__ cur) {
  __shared__ int sdata[1024];
  int t = blockIdx.x;
  int tid = threadIdx.x;
  const int* c = cnt + t * kN;
  int v0 = c[tid * 4], v1 = c[tid * 4 + 1], v2 = c[tid * 4 + 2], v3 = c[tid * 4 + 3];
  int s = v0 + v1 + v2 + v3;
  sdata[tid] = s;
  __syncthreads();
  for (int d = 1; d < 1024; d <<= 1) {
    int add = (tid >= d) ? sdata[tid - d] : 0;
    __syncthreads();
    sdata[tid] += add;
    __syncthreads();
  }
  int base = sdata[tid] - s;
  int o = t * kN + tid * 4;
  off[o] = base;            cur[o] = base;
  off[o + 1] = base + v0;   cur[o + 1] = base + v0;
  off[o + 2] = base + v0 + v1;        cur[o + 2] = base + v0 + v1;
  off[o + 3] = base + v0 + v1 + v2;   cur[o + 3] = base + v0 + v1 + v2;
}

// ---------------------------------------------------------------------------
// Stage 2c: CSR placement — csr[t*E + pos] = src
// ---------------------------------------------------------------------------
__global__ __launch_bounds__(256) void place_kernel(
    const int* __restrict__ ei, int* __restrict__ cur, int* __restrict__ csr) {
  int i = blockIdx.x * 256 + threadIdx.x;
  int t = i >> 15, e = i & (kE - 1);
  int src = ei[t * 2 * kE + e];
  int dst = ei[t * 2 * kE + kE + e];
  int pos = atomicAdd(&cur[t * kN + dst], 1);
  csr[t * kE + pos] = src;
}

// ---------------------------------------------------------------------------
// Stage 2d: gather + combine. wave per (t,dst); lane = (batch, channel-quad).
// ---------------------------------------------------------------------------
__global__ __launch_bounds__(256) void gather_kernel(
    const float* __restrict__ h, const int* __restrict__ csr,
    const int* __restrict__ off, const int* __restrict__ cnt,
    float* __restrict__ x) {
  int wv = blockIdx.x * 4 + (threadIdx.x >> 6);   // 0 .. T*N-1
  int t = wv >> 12, d = wv & (kN - 1);
  int lane = threadIdx.x & 63;
  int b = lane >> 4, cq = lane & 15;              // batch, channel quad
  int o = off[t * kN + d];
  int c = cnt[t * kN + d];
  const float* hb = h + (size_t)t * kBN * 64;
  const int* cs = csr + t * kE + o;
  float sx = 0.f, sy = 0.f, sz = 0.f, sw = 0.f;
  size_t bbase = (size_t)b * kN;
  int j = 0;
  for (; j + 4 <= c; j += 4) {
    int i0 = cs[j], i1 = cs[j + 1], i2 = cs[j + 2], i3 = cs[j + 3];
    float4 v0 = *(const float4*)&hb[(bbase + i0) * 64 + cq * 4];
    float4 v1 = *(const float4*)&hb[(bbase + i1) * 64 + cq * 4];
    float4 v2 = *(const float4*)&hb[(bbase + i2) * 64 + cq * 4];
    float4 v3 = *(const float4*)&hb[(bbase + i3) * 64 + cq * 4];
    sx += v0.x + v1.x + v2.x + v3.x;
    sy += v0.y + v1.y + v2.y + v3.y;
    sz += v0.z + v1.z + v2.z + v3.z;
    sw += v0.w + v1.w + v2.w + v3.w;
  }
  for (; j < c; ++j) {
    int i0 = cs[j];
    float4 v0 = *(const float4*)&hb[(bbase + i0) * 64 + cq * 4];
    sx += v0.x; sy += v0.y; sz += v0.z; sw += v0.w;
  }
  float4 hv = *(const float4*)&hb[(bbase + d) * 64 + cq * 4];
  float4 ov;
  if (c > 0) {
    float inv = 1.f / (float)c;
    ov.x = (hv.x + sx * inv) * 0.5f;
    ov.y = (hv.y + sy * inv) * 0.5f;
    ov.z = (hv.z + sz * inv) * 0.5f;
    ov.w = (hv.w + sw * inv) * 0.5f;
  } else {
    ov = hv;
  }
  *(float4*)&x[(size_t)t * kBN * 64 + (bbase + d) * 64 + cq * 4] = ov;
}

// ---------------------------------------------------------------------------
// Stage 3: one LSTM layer via split-precision fp16 MFMA (unchanged from R2).
// ---------------------------------------------------------------------------
__global__ __launch_bounds__(256, 1) void lstm_kernel(
    const float* __restrict__ xin, float* __restrict__ xout,
    const float* __restrict__ wih, const float* __restrict__ whh,
    const float* __restrict__ bih, const float* __restrict__ bhh) {
  __shared__ __align__(16) _Float16 wfrag[2][2][16][2][512];  // 131072 B
  __shared__ __align__(16) _Float16 hfrag[4][2][2][512];      // 16384 B

  int tid = threadIdx.x;
  for (int idx = tid; idx < 2 * 256 * 16; idx += 256) {
    int mat = idx >> 12;
    int r = (idx >> 4) & 255;
    int k4 = idx & 15;
    const float* W = mat ? whh : wih;
    float4 v = *(const float4*)&W[r * 64 + k4 * 4];
    int k = k4 * 4;
    int nt = r >> 4, i = r & 15, ks = k >> 5, q = (k >> 3) & 3, j0 = k & 7;
    int lane = q * 16 + i;
    _Float16* dh = &wfrag[mat][0][nt][ks][lane * 8 + j0];
    _Float16* dl = &wfrag[mat][1][nt][ks][lane * 8 + j0];
    float vv[4] = {v.x, v.y, v.z, v.w};
#pragma unroll
    for (int u = 0; u < 4; ++u) {
      _Float16 hh = (_Float16)vv[u];
      dh[u] = hh;
      dl[u] = (_Float16)(vv[u] - (float)hh);
    }
  }

  int w = tid >> 6, lane = tid & 63;
  int q = lane >> 4, i = lane & 15;
  int s0 = blockIdx.x * 64;
  float bias4[4];
#pragma unroll
  for (int g = 0; g < 4; ++g) {
    int col = g * 64 + w * 16 + i;
    bias4[g] = bih[col] + bhh[col];
  }
  float cstate[4][4];
#pragma unroll
  for (int Mt = 0; Mt < 4; ++Mt)
#pragma unroll
    for (int r = 0; r < 4; ++r) cstate[Mt][r] = 0.f;

  int ch = w * 16 + i;
  int ks2 = ch >> 5, q2 = (ch >> 3) & 3, j2 = ch & 7;

  __syncthreads();

  for (int t = 0; t < kT; ++t) {
    f16x8 xa[4][2][2];
#pragma unroll
    for (int Mt = 0; Mt < 4; ++Mt)
#pragma unroll
      for (int ks = 0; ks < 2; ++ks) {
        const float* p = xin + ((size_t)t * kBN + s0 + Mt * 16 + i) * 64 + ks * 32 + q * 8;
        split8(p, xa[Mt][ks][0], xa[Mt][ks][1]);
      }
    f16x8 ha[4][2][2];
    if (t > 0) {
#pragma unroll
      for (int Mt = 0; Mt < 4; ++Mt)
#pragma unroll
        for (int ks = 0; ks < 2; ++ks) {
          ha[Mt][ks][0] = *(const f16x8*)&hfrag[Mt][ks][0][lane * 8];
          ha[Mt][ks][1] = *(const f16x8*)&hfrag[Mt][ks][1][lane * 8];
        }
    } else {
#pragma unroll
      for (int Mt = 0; Mt < 4; ++Mt)
#pragma unroll
        for (int ks = 0; ks < 2; ++ks) {
          ha[Mt][ks][0] = (f16x8)0;
          ha[Mt][ks][1] = (f16x8)0;
        }
    }
    __syncthreads();

    f32x4 acc[4][4];
#pragma unroll
    for (int Mt = 0; Mt < 4; ++Mt)
#pragma unroll
      for (int g = 0; g < 4; ++g) {
        acc[Mt][g][0] = bias4[g]; acc[Mt][g][1] = bias4[g];
        acc[Mt][g][2] = bias4[g]; acc[Mt][g][3] = bias4[g];
      }
#pragma unroll
    for (int g = 0; g < 4; ++g) {
      int nt = g * 4 + w;
      f16x8 bf[2][2][2];
#pragma unroll
      for (int mat = 0; mat < 2; ++mat)
#pragma unroll
        for (int ks = 0; ks < 2; ++ks) {
          bf[mat][ks][0] = *(const f16x8*)&wfrag[mat][0][nt][ks][lane * 8];
          bf[mat][ks][1] = *(const f16x8*)&wfrag[mat][1][nt][ks][lane * 8];
        }
#pragma unroll
      for (int Mt = 0; Mt < 4; ++Mt) {
        f32x4 a = acc[Mt][g];
#pragma unroll
        for (int ks = 0; ks < 2; ++ks) {
          a = __builtin_amdgcn_mfma_f32_16x16x32_f16(xa[Mt][ks][0], bf[0][ks][0], a, 0, 0, 0);
          a = __builtin_amdgcn_mfma_f32_16x16x32_f16(xa[Mt][ks][0], bf[0][ks][1], a, 0, 0, 0);
          a = __builtin_amdgcn_mfma_f32_16x16x32_f16(xa[Mt][ks][1], bf[0][ks][0], a, 0, 0, 0);
          a = __builtin_amdgcn_mfma_f32_16x16x32_f16(ha[Mt][ks][0], bf[1][ks][0], a, 0, 0, 0);
          a = __builtin_amdgcn_mfma_f32_16x16x32_f16(ha[Mt][ks][0], bf[1][ks][1], a, 0, 0, 0);
          a = __builtin_amdgcn_mfma_f32_16x16x32_f16(ha[Mt][ks][1], bf[1][ks][0], a, 0, 0, 0);
        }
        acc[Mt][g] = a;
      }
    }

#pragma unroll
    for (int Mt = 0; Mt < 4; ++Mt)
#pragma unroll
      for (int r = 0; r < 4; ++r) {
        float zi = acc[Mt][0][r], zf = acc[Mt][1][r];
        float zg = acc[Mt][2][r], zo = acc[Mt][3][r];
        float ig = sigm(zi), fg = sigm(zf), gg = tanh_(zg), og = sigm(zo);
        float c = fg * cstate[Mt][r] + ig * gg;
        cstate[Mt][r] = c;
        float hv = og * tanh_(c);
        int row = q * 4 + r;
        xout[((size_t)t * kBN + s0 + Mt * 16 + row) * 64 + ch] = hv;
        _Float16 hh = (_Float16)hv;
        int lane2 = q2 * 16 + row;
        hfrag[Mt][ks2][0][lane2 * 8 + j2] = hh;
        hfrag[Mt][ks2][1][lane2 * 8 + j2] = (_Float16)(hv - (float)hh);
      }
    __syncthreads();
  }
}

// ---------------------------------------------------------------------------
// Weight-fragment stagers for the head (B-frag order, fp16 hi/lo).
// layout [nt][ks][hl][512] with offset ((nt*KS+ks)*2+hl)*512
// ---------------------------------------------------------------------------
__device__ __forceinline__ void stage_frags64(const float* W, _Float16* base,
                                              int O, int tid) {
  int total = O * 16;
  for (int idx = tid; idx < total; idx += 256) {
    int r = idx >> 4, k4 = idx & 15;
    float4 v = *(const float4*)&W[r * 64 + k4 * 4];
    int k = k4 * 4;
    int nt = r >> 4, ii = r & 15, ks = k >> 5, qq = (k >> 3) & 3, j0 = k & 7;
    _Float16* dh = base + ((nt * 2 + ks) * 2) * 512 + (qq * 16 + ii) * 8 + j0;
    _Float16* dl = dh + 512;
    float vv[4] = {v.x, v.y, v.z, v.w};
#pragma unroll
    for (int u = 0; u < 4; ++u) {
      _Float16 hh = (_Float16)vv[u];
      dh[u] = hh;
      dl[u] = (_Float16)(vv[u] - (float)hh);
    }
  }
}

__device__ __forceinline__ void stage_frags128(const float* W, _Float16* base,
                                               int O, int tid) {
  int total = O * 32;
  for (int idx = tid; idx < total; idx += 256) {
    int r = idx >> 5, k4 = idx & 31;
    float4 v = *(const float4*)&W[r * 128 + k4 * 4];
    int k = k4 * 4;
    int nt = r >> 4, ii = r & 15, ks = k >> 5, qq = (k >> 3) & 3, j0 = k & 7;
    _Float16* dh = base + ((nt * 4 + ks) * 2) * 512 + (qq * 16 + ii) * 8 + j0;
    _Float16* dl = dh + 512;
    float vv[4] = {v.x, v.y, v.z, v.w};
#pragma unroll
    for (int u = 0; u < 4; ++u) {
      _Float16 hh = (_Float16)vv[u];
      dh[u] = hh;
      dl[u] = (_Float16)(vv[u] - (float)hh);
    }
  }
}

// ---------------------------------------------------------------------------
// Stage 4 v2: fused attention + head MLP, all GEMMs via fp16x3 MFMA.
// Block = 256 thr (4 waves) = 64 seqs. Attention: thread = (head=wave, seq=lane).
// LDS: 84 KB weight-frag region (reused across phase A/B) + 36 KB transposed
// activation buffer [col][seq] stride 68 (conflict-free lane-stride-1 reads).
// ---------------------------------------------------------------------------
__global__ __launch_bounds__(256, 1) void head_kernel(
    const float* __restrict__ x, const float* __restrict__ win,
    const float* __restrict__ bin, const float* __restrict__ wout,
    const float* __restrict__ bout, const float* __restrict__ pw1,
    const float* __restrict__ pb1, const float* __restrict__ pw2,
    const float* __restrict__ pb2, const float* __restrict__ pw3,
    const float* __restrict__ pb3, float* __restrict__ out) {
  __shared__ __align__(16) float smem[30720];   // 120 KB
  _Float16* wb = (_Float16*)smem;               // 84 KB weight frags (43008 f16)
  float* buf = smem + 21504;                    // 36 KB activations (9216 f32)
  // phase A: WQ at 0 (8192), WKV at 8192 (16384)
  // phase B: WOUT at 0 (8192), W1 at 8192 (16384), W2 at 24576 (16384), W3 at 40960 (2048)

  int tid = threadIdx.x;
  int w = tid >> 6, lane = tid & 63;
  int q = lane >> 4, i = lane & 15;
  int s0 = blockIdx.x * 64;

  stage_frags64(win, wb, 64, tid);                 // Wq
  stage_frags64(win + 64 * 64, wb + 8192, 128, tid);  // Wkv
  __syncthreads();

  // ---- q projection at t=15 (wave w: Mt=w, Nt 0..3) ----
  {
    f16x8 ah[2], al[2];
#pragma unroll
    for (int ks = 0; ks < 2; ++ks)
      split8(x + ((size_t)15 * kBN + s0 + w * 16 + i) * 64 + ks * 32 + q * 8,
             ah[ks], al[ks]);
#pragma unroll
    for (int nt = 0; nt < 4; ++nt) {
      float bias = bin[nt * 16 + i];
      f32x4 acc = {bias, bias, bias, bias};
#pragma unroll
      for (int ks = 0; ks < 2; ++ks) {
        const _Float16* bp = wb + ((nt * 2 + ks) * 2) * 512 + lane * 8;
        acc = mm3(ah[ks], al[ks], *(const f16x8*)bp, *(const f16x8*)(bp + 512), acc);
      }
      *(float4*)&buf[(nt * 16 + i) * 68 + w * 16 + q * 4] = *(float4*)&acc;
    }
  }
  __syncthreads();
  float qreg[16];
#pragma unroll
  for (int d = 0; d < 16; ++d) qreg[d] = buf[(w * 16 + d) * 68 + lane];
  __syncthreads();

  // ---- t loop: kv projection via MFMA + online-softmax attention ----
  float m = -1e30f, l = 0.f;
  float o[16];
#pragma unroll
  for (int d = 0; d < 16; ++d) o[d] = 0.f;

  for (int t = 0; t < kT; ++t) {
    f16x8 xah[4][2], xal[4][2];
#pragma unroll
    for (int Mt = 0; Mt < 4; ++Mt)
#pragma unroll
      for (int ks = 0; ks < 2; ++ks)
        split8(x + ((size_t)t * kBN + s0 + Mt * 16 + i) * 64 + ks * 32 + q * 8,
               xah[Mt][ks], xal[Mt][ks]);
#pragma unroll
    for (int u = 0; u < 2; ++u) {
      int nt = 2 * w + u;                    // cols 0..63 = k, 64..127 = v
      float bias = bin[64 + nt * 16 + i];
      f16x8 bh[2], bl[2];
#pragma unroll
      for (int ks = 0; ks < 2; ++ks) {
        const _Float16* bp = wb + 8192 + ((nt * 2 + ks) * 2) * 512 + lane * 8;
        bh[ks] = *(const f16x8*)bp;
        bl[ks] = *(const f16x8*)(bp + 512);
      }
#pragma unroll
      for (int Mt = 0; Mt < 4; ++Mt) {
        f32x4 acc = {bias, bias, bias, bias};
#pragma unroll
        for (int ks = 0; ks < 2; ++ks)
          acc = mm3(xah[Mt][ks], xal[Mt][ks], bh[ks], bl[ks], acc);
        *(float4*)&buf[(nt * 16 + i) * 68 + Mt * 16 + q * 4] = *(float4*)&acc;
      }
    }
    __syncthreads();
    // attention update: thread (head=w, seq=lane)
    float sc = 0.f;
#pragma unroll
    for (int d = 0; d < 16; ++d) sc += qreg[d] * buf[(w * 16 + d) * 68 + lane];
    sc *= 0.25f;   // 1/sqrt(HD=16)
    float mn = fmaxf(m, sc);
    float alpha = __expf(m - mn);
    float p = __expf(sc - mn);
    l = l * alpha + p;
#pragma unroll
    for (int d = 0; d < 16; ++d)
      o[d] = o[d] * alpha + p * buf[(64 + w * 16 + d) * 68 + lane];
    m = mn;
    __syncthreads();
  }

  // ---- write normalized o (transposed, cols 0..63) ----
  float linv = 1.f / l;
#pragma unroll
  for (int d = 0; d < 16; ++d) buf[(w * 16 + d) * 68 + lane] = o[d] * linv;
  __syncthreads();

  // ---- restage phase-B weights ----
  stage_frags64(wout, wb, 64, tid);
  stage_frags64(pw1, wb + 8192, 128, tid);
  stage_frags128(pw2, wb + 24576, 64, tid);
  for (int idx = tid; idx < 256; idx += 256) {   // pw3 padded to 16 rows
    int r = idx >> 4, k4 = idx & 15;
    float4 v = {0.f, 0.f, 0.f, 0.f};
    if (r < kNC) v = *(const float4*)&pw3[r * 64 + k4 * 4];
    int k = k4 * 4;
    int ks = k >> 5, qq = (k >> 3) & 3, j0 = k & 7;
    _Float16* dh = wb + 40960 + (ks * 2) * 512 + (qq * 16 + r) * 8 + j0;
    _Float16* dl = dh + 512;
    float vv[4] = {v.x, v.y, v.z, v.w};
#pragma unroll
    for (int u = 0; u < 4; ++u) {
      _Float16 hh = (_Float16)vv[u];
      dh[u] = hh;
      dl[u] = (_Float16)(vv[u] - (float)hh);
    }
  }
  __syncthreads();

  int seq = w * 16 + i;   // this lane's A-row (Mt = w)

  // ---- out projection: fin = o @ wout^T + bout  -> buf[4352..8704) ----
  {
    f16x8 ah[2], al[2];
    split8T(buf, q * 8, seq, ah[0], al[0]);
    split8T(buf, 32 + q * 8, seq, ah[1], al[1]);
    // fin region [4352,8704) disjoint from o region [0,4352): no barrier needed
#pragma unroll
    for (int nt = 0; nt < 4; ++nt) {
      float bias = bout[nt * 16 + i];
      f32x4 acc = {bias, bias, bias, bias};
#pragma unroll
      for (int ks = 0; ks < 2; ++ks) {
        const _Float16* bp = wb + ((nt * 2 + ks) * 2) * 512 + lane * 8;
        acc = mm3(ah[ks], al[ks], *(const f16x8*)bp, *(const f16x8*)(bp + 512), acc);
      }
      *(float4*)&buf[4352 + (nt * 16 + i) * 68 + w * 16 + q * 4] = *(float4*)&acc;
    }
  }
  __syncthreads();

  // ---- z1 = relu(fin @ pw1^T + pb1) -> buf[0..8704) ----
  {
    f16x8 ah[2], al[2];
    split8T(buf + 4352, q * 8, seq, ah[0], al[0]);
    split8T(buf + 4352, 32 + q * 8, seq, ah[1], al[1]);
    __syncthreads();   // all fin reads done before overlapping z1 writes
#pragma unroll
    for (int nt = 0; nt < 8; ++nt) {
      float bias = pb1[nt * 16 + i];
      f32x4 acc = {bias, bias, bias, bias};
#pragma unroll
      for (int ks = 0; ks < 2; ++ks) {
        const _Float16* bp = wb + 8192 + ((nt * 2 + ks) * 2) * 512 + lane * 8;
        acc = mm3(ah[ks], al[ks], *(const f16x8*)bp, *(const f16x8*)(bp + 512), acc);
      }
      f32x4 r4;
#pragma unroll
      for (int r = 0; r < 4; ++r) r4[r] = fmaxf(acc[r], 0.f);
      *(float4*)&buf[(nt * 16 + i) * 68 + w * 16 + q * 4] = *(float4*)&r4;
    }
  }
  __syncthreads();

  // ---- z2 = relu(z1 @ pw2^T + pb2) -> buf[0..4352) ----
  {
    f16x8 ah[4], al[4];
#pragma unroll
    for (int ks = 0; ks < 4; ++ks)
      split8T(buf, ks * 32 + q * 8, seq, ah[ks], al[ks]);
    __syncthreads();   // all z1 reads done before overlapping z2 writes
#pragma unroll
    for (int nt = 0; nt < 4; ++nt) {
      float bias = pb2[nt * 16 + i];
      f32x4 acc = {bias, bias, bias, bias};
#pragma unroll
      for (int ks = 0; ks < 4; ++ks) {
        const _Float16* bp = wb + 24576 + ((nt * 4 + ks) * 2) * 512 + lane * 8;
        acc = mm3(ah[ks], al[ks], *(const f16x8*)bp, *(const f16x8*)(bp + 512), acc);
      }
      f32x4 r4;
#pragma unroll
      for (int r = 0; r < 4; ++r) r4[r] = fmaxf(acc[r], 0.f);
      *(float4*)&buf[(nt * 16 + i) * 68 + w * 16 + q * 4] = *(float4*)&r4;
    }
  }
  __syncthreads();

  // ---- logits = z2 @ pw3^T + pb3 -> global ----
  {
    f16x8 ah[2], al[2];
    split8T(buf, q * 8, seq, ah[0], al[0]);
    split8T(buf, 32 + q * 8, seq, ah[1], al[1]);
    f32x4 acc = {0.f, 0.f, 0.f, 0.f};
#pragma unroll
    for (int ks = 0; ks < 2; ++ks) {
      const _Float16* bp = wb + 40960 + (ks * 2) * 512 + lane * 8;
      acc = mm3(ah[ks], al[ks], *(const f16x8*)bp, *(const f16x8*)(bp + 512), acc);
    }
    if (i < kNC) {
      float bb = pb3[i];
#pragma unroll
      for (int r = 0; r < 4; ++r)
        out[(size_t)(s0 + w * 16 + q * 4 + r) * kNC + i] = acc[r] + bb;
    }
  }
}

// ---------------------------------------------------------------------------
extern "C" void kernel_launch(void* const* d_in, const int* in_sizes, int n_in,
                              void* d_out, int out_size, void* d_ws, size_t ws_size,
                              hipStream_t stream) {
  const float* nf    = (const float*)d_in[0];
  const int*   ei    = (const int*)d_in[1];
  const float* sc_w1 = (const float*)d_in[2];
  const float* sc_b1 = (const float*)d_in[3];
  const float* sc_w2 = (const float*)d_in[4];
  const float* sc_b2 = (const float*)d_in[5];
  const float* wih0  = (const float*)d_in[6];
  const float* whh0  = (const float*)d_in[7];
  const float* bih0  = (const float*)d_in[8];
  const float* bhh0  = (const float*)d_in[9];
  const float* wih1  = (const float*)d_in[10];
  const float* whh1  = (const float*)d_in[11];
  const float* bih1  = (const float*)d_in[12];
  const float* bhh1  = (const float*)d_in[13];
  const float* win   = (const float*)d_in[14];
  const float* bin   = (const float*)d_in[15];
  const float* wout  = (const float*)d_in[16];
  const float* bout  = (const float*)d_in[17];
  const float* pw1   = (const float*)d_in[18];
  const float* pb1   = (const float*)d_in[19];
  const float* pw2   = (const float*)d_in[20];
  const float* pb2   = (const float*)d_in[21];
  const float* pw3   = (const float*)d_in[22];
  const float* pb3   = (const float*)d_in[23];
  float* out = (float*)d_out;

  const size_t NB = (size_t)kT * kBN * 64;  // 16,777,216 floats per buffer
  float* A = (float*)d_ws;   // conv output h; later LSTM ping buffer
  float* C = A + NB;         // x after aggregation; LSTM pong buffer
  int* cnt = (int*)(C + NB);           // T*N
  int* off = cnt + kT * kN;            // T*N
  int* cur = off + kT * kN;            // T*N
  int* csr = cur + kT * kN;            // T*E

  hipMemsetAsync(cnt, 0, (size_t)kT * kN * sizeof(int), stream);

  conv_kernel<<<1024, 256, 0, stream>>>(nf, sc_w1, sc_b1, sc_w2, sc_b2, A);
  count_kernel<<<2048, 256, 0, stream>>>(ei, cnt);
  scan_kernel<<<16, 1024, 0, stream>>>(cnt, off, cur);
  place_kernel<<<2048, 256, 0, stream>>>(ei, cur, csr);
  gather_kernel<<<16384, 256, 0, stream>>>(A, csr, off, cnt, C);
  lstm_kernel<<<256, 256, 0, stream>>>(C, A, wih0, whh0, bih0, bhh0);
  lstm_kernel<<<256, 256, 0, stream>>>(A, C, wih1, whh1, bih1, bhh1);
  head_kernel<<<256, 256, 0, stream>>>(C, win, bin, wout, bout,
                                       pw1, pb1, pw2, pb2, pw3, pb3, out);
}

// Round 5
// 532.359 us; speedup vs baseline: 3.5708x; 1.1125x over previous
//
#include <hip/hip_runtime.h>

// Problem constants
constexpr int kB  = 4;
constexpr int kT  = 16;
constexpr int kN  = 4096;
constexpr int kBN = kB * kN;      // 16384
constexpr int kE  = 32768;
constexpr int kNC = 13;

typedef _Float16 f16x8 __attribute__((ext_vector_type(8)));
typedef float f32x4 __attribute__((ext_vector_type(4)));

__device__ __forceinline__ float rl(float v, int l) {
  return __int_as_float(__builtin_amdgcn_readlane(__float_as_int(v), l));
}
__device__ __forceinline__ float sigm(float x) { return 1.f / (1.f + __expf(-x)); }
__device__ __forceinline__ float tanh_(float x) {
  float e = __expf(2.f * x);
  return 1.f - 2.f / (e + 1.f);
}

__device__ __forceinline__ f32x4 mm3(f16x8 ah, f16x8 al, f16x8 bh, f16x8 bl, f32x4 acc) {
  acc = __builtin_amdgcn_mfma_f32_16x16x32_f16(ah, bh, acc, 0, 0, 0);
  acc = __builtin_amdgcn_mfma_f32_16x16x32_f16(ah, bl, acc, 0, 0, 0);
  acc = __builtin_amdgcn_mfma_f32_16x16x32_f16(al, bh, acc, 0, 0, 0);
  return acc;
}

// split 8 consecutive fp32 into hi/lo fp16 A-frag registers
__device__ __forceinline__ void split8(const float* p, f16x8& hi, f16x8& lo) {
  float4 u0 = *(const float4*)p, u1 = *(const float4*)(p + 4);
  float vv[8] = {u0.x, u0.y, u0.z, u0.w, u1.x, u1.y, u1.z, u1.w};
#pragma unroll
  for (int j = 0; j < 8; ++j) {
    _Float16 hj = (_Float16)vv[j];
    hi[j] = hj;
    lo[j] = (_Float16)(vv[j] - (float)hj);
  }
}

__device__ __forceinline__ void split8v(const float4& u0, const float4& u1,
                                        f16x8& hi, f16x8& lo) {
  float vv[8] = {u0.x, u0.y, u0.z, u0.w, u1.x, u1.y, u1.z, u1.w};
#pragma unroll
  for (int j = 0; j < 8; ++j) {
    _Float16 hj = (_Float16)vv[j];
    hi[j] = hj;
    lo[j] = (_Float16)(vv[j] - (float)hj);
  }
}

// split from transposed LDS activation buffer [col][seq], row stride 68
__device__ __forceinline__ void split8T(const float* base, int kbase, int seq,
                                        f16x8& hi, f16x8& lo) {
  float vv[8];
#pragma unroll
  for (int j = 0; j < 8; ++j) vv[j] = base[(kbase + j) * 68 + seq];
#pragma unroll
  for (int j = 0; j < 8; ++j) {
    _Float16 hj = (_Float16)vv[j];
    hi[j] = hj;
    lo[j] = (_Float16)(vv[j] - (float)hj);
  }
}

// ---------------------------------------------------------------------------
// Stage 1: per-node 2-layer MLP (8 -> 64 relu -> 64), thread-per-node.
// ---------------------------------------------------------------------------
__global__ __launch_bounds__(256) void conv_kernel(
    const float* __restrict__ nf, const float* __restrict__ w1,
    const float* __restrict__ b1, const float* __restrict__ w2,
    const float* __restrict__ b2, float* __restrict__ hout) {
  int node = blockIdx.x * 256 + threadIdx.x;   // flat (b,t,n), 262144 total
  int b = node >> 16;
  int t = (node >> 12) & 15;
  int n = node & 4095;
  const float4* src = (const float4*)(nf + (size_t)node * 8);
  float4 x0 = src[0], x1 = src[1];
  float x[8] = {x0.x, x0.y, x0.z, x0.w, x1.x, x1.y, x1.z, x1.w};
  float h1[64];
#pragma unroll
  for (int h = 0; h < 64; ++h) {
    float a = b1[h];
#pragma unroll
    for (int f = 0; f < 8; ++f) a += w1[h * 8 + f] * x[f];
    h1[h] = fmaxf(a, 0.f);
  }
  float* dst = hout + ((size_t)t * kBN + b * kN + n) * 64;
#pragma unroll 1
  for (int g = 0; g < 64; g += 4) {
    float4 acc = {b2[g], b2[g + 1], b2[g + 2], b2[g + 3]};
#pragma unroll
    for (int h = 0; h < 64; ++h) {
      float hh = h1[h];
      acc.x += w2[(g + 0) * 64 + h] * hh;
      acc.y += w2[(g + 1) * 64 + h] * hh;
      acc.z += w2[(g + 2) * 64 + h] * hh;
      acc.w += w2[(g + 3) * 64 + h] * hh;
    }
    *(float4*)(dst + g) = acc;
  }
}

// ---------------------------------------------------------------------------
// Stage 2a: per-(t,dst) edge count (int atomics only)
// ---------------------------------------------------------------------------
__global__ __launch_bounds__(256) void count_kernel(
    const int* __restrict__ ei, int* __restrict__ cnt) {
  int i = blockIdx.x * 256 + threadIdx.x;   // over T*E
  int t = i >> 15, e = i & (kE - 1);
  int dst = ei[t * 2 * kE + kE + e];
  atomicAdd(&cnt[t * kN + dst], 1);
}

// ---------------------------------------------------------------------------
// Stage 2b: per-t exclusive scan over 4096 counts -> offsets + cursor copy.
// ---------------------------------------------------------------------------
__global__ __launch_bounds__(1024) void scan_kernel(
    const int* __restrict__ cnt, int* __restrict__ off, int* __restrict__ cur) {
  __shared__ int sdata[1024];
  int t = blockIdx.x;
  int tid = threadIdx.x;
  const int* c = cnt + t * kN;
  int v0 = c[tid * 4], v1 = c[tid * 4 + 1], v2 = c[tid * 4 + 2], v3 = c[tid * 4 + 3];
  int s = v0 + v1 + v2 + v3;
  sdata[tid] = s;
  __syncthreads();
  for (int d = 1; d < 1024; d <<= 1) {
    int add = (tid >= d) ? sdata[tid - d] : 0;
    __syncthreads();
    sdata[tid] += add;
    __syncthreads();
  }
  int base = sdata[tid] - s;
  int o = t * kN + tid * 4;
  off[o] = base;            cur[o] = base;
  off[o + 1] = base + v0;   cur[o + 1] = base + v0;
  off[o + 2] = base + v0 + v1;        cur[o + 2] = base + v0 + v1;
  off[o + 3] = base + v0 + v1 + v2;   cur[o + 3] = base + v0 + v1 + v2;
}

// ---------------------------------------------------------------------------
// Stage 2c: CSR placement — csr[t*E + pos] = src
// ---------------------------------------------------------------------------
__global__ __launch_bounds__(256) void place_kernel(
    const int* __restrict__ ei, int* __restrict__ cur, int* __restrict__ csr) {
  int i = blockIdx.x * 256 + threadIdx.x;
  int t = i >> 15, e = i & (kE - 1);
  int src = ei[t * 2 * kE + e];
  int dst = ei[t * 2 * kE + kE + e];
  int pos = atomicAdd(&cur[t * kN + dst], 1);
  csr[t * kE + pos] = src;
}

// ---------------------------------------------------------------------------
// Stage 2d: gather + combine. wave per (t,dst); lane = (batch, channel-quad).
// ---------------------------------------------------------------------------
__global__ __launch_bounds__(256) void gather_kernel(
    const float* __restrict__ h, const int* __restrict__ csr,
    const int* __restrict__ off, const int* __restrict__ cnt,
    float* __restrict__ x) {
  int wv = blockIdx.x * 4 + (threadIdx.x >> 6);   // 0 .. T*N-1
  int t = wv >> 12, d = wv & (kN - 1);
  int lane = threadIdx.x & 63;
  int b = lane >> 4, cq = lane & 15;              // batch, channel quad
  int o = off[t * kN + d];
  int c = cnt[t * kN + d];
  const float* hb = h + (size_t)t * kBN * 64;
  const int* cs = csr + t * kE + o;
  float sx = 0.f, sy = 0.f, sz = 0.f, sw = 0.f;
  size_t bbase = (size_t)b * kN;
  int j = 0;
  for (; j + 4 <= c; j += 4) {
    int i0 = cs[j], i1 = cs[j + 1], i2 = cs[j + 2], i3 = cs[j + 3];
    float4 v0 = *(const float4*)&hb[(bbase + i0) * 64 + cq * 4];
    float4 v1 = *(const float4*)&hb[(bbase + i1) * 64 + cq * 4];
    float4 v2 = *(const float4*)&hb[(bbase + i2) * 64 + cq * 4];
    float4 v3 = *(const float4*)&hb[(bbase + i3) * 64 + cq * 4];
    sx += v0.x + v1.x + v2.x + v3.x;
    sy += v0.y + v1.y + v2.y + v3.y;
    sz += v0.z + v1.z + v2.z + v3.z;
    sw += v0.w + v1.w + v2.w + v3.w;
  }
  for (; j < c; ++j) {
    int i0 = cs[j];
    float4 v0 = *(const float4*)&hb[(bbase + i0) * 64 + cq * 4];
    sx += v0.x; sy += v0.y; sz += v0.z; sw += v0.w;
  }
  float4 hv = *(const float4*)&hb[(bbase + d) * 64 + cq * 4];
  float4 ov;
  if (c > 0) {
    float inv = 1.f / (float)c;
    ov.x = (hv.x + sx * inv) * 0.5f;
    ov.y = (hv.y + sy * inv) * 0.5f;
    ov.z = (hv.z + sz * inv) * 0.5f;
    ov.w = (hv.w + sw * inv) * 0.5f;
  } else {
    ov = hv;
  }
  *(float4*)&x[(size_t)t * kBN * 64 + (bbase + d) * 64 + cq * 4] = ov;
}

// ---------------------------------------------------------------------------
// Stage 3 v2: one LSTM layer via fp16x3 MFMA. Block = 512 thr (8 waves),
// 64 seqs/block. Wave = (cb = w&3: channel block, mh = w>>2: Mt pair) ->
// 96 MFMA/wave/t, 2 waves/SIMD (vs 1 before). x(t+1) prefetched into
// registers before the MFMA section to hide HBM latency.
// LDS: W frags 128 KB + hfrag 16 KB = 144 KB (1 block/CU).
// ---------------------------------------------------------------------------
__global__ __launch_bounds__(512, 2) void lstm_kernel(
    const float* __restrict__ xin, float* __restrict__ xout,
    const float* __restrict__ wih, const float* __restrict__ whh,
    const float* __restrict__ bih, const float* __restrict__ bhh) {
  __shared__ __align__(16) _Float16 wfrag[2][2][16][2][512];  // 131072 B
  __shared__ __align__(16) _Float16 hfrag[4][2][2][512];      // 16384 B

  int tid = threadIdx.x;
  for (int idx = tid; idx < 2 * 256 * 16; idx += 512) {
    int mat = idx >> 12;
    int r = (idx >> 4) & 255;
    int k4 = idx & 15;
    const float* W = mat ? whh : wih;
    float4 v = *(const float4*)&W[r * 64 + k4 * 4];
    int k = k4 * 4;
    int nt = r >> 4, i = r & 15, ks = k >> 5, q = (k >> 3) & 3, j0 = k & 7;
    int lane = q * 16 + i;
    _Float16* dh = &wfrag[mat][0][nt][ks][lane * 8 + j0];
    _Float16* dl = &wfrag[mat][1][nt][ks][lane * 8 + j0];
    float vv[4] = {v.x, v.y, v.z, v.w};
#pragma unroll
    for (int u = 0; u < 4; ++u) {
      _Float16 hh = (_Float16)vv[u];
      dh[u] = hh;
      dl[u] = (_Float16)(vv[u] - (float)hh);
    }
  }

  int w = tid >> 6, lane = tid & 63;
  int cb = w & 3, mh = w >> 2;       // channel block, Mt pair
  int q = lane >> 4, i = lane & 15;
  int s0 = blockIdx.x * 64;
  float bias4[4];
#pragma unroll
  for (int g = 0; g < 4; ++g) {
    int col = g * 64 + cb * 16 + i;
    bias4[g] = bih[col] + bhh[col];
  }
  float cstate[2][4];
#pragma unroll
  for (int ml = 0; ml < 2; ++ml)
#pragma unroll
    for (int r = 0; r < 4; ++r) cstate[ml][r] = 0.f;

  int ch = cb * 16 + i;
  int ks2 = ch >> 5, q2 = (ch >> 3) & 3, j2 = ch & 7;

  // prologue: load x(0)
  float4 raw[2][2][2];   // [ml][ks][half]
#pragma unroll
  for (int ml = 0; ml < 2; ++ml)
#pragma unroll
    for (int ks = 0; ks < 2; ++ks) {
      const float* p = xin + ((size_t)(s0 + (2 * mh + ml) * 16 + i)) * 64 + ks * 32 + q * 8;
      raw[ml][ks][0] = *(const float4*)p;
      raw[ml][ks][1] = *(const float4*)(p + 4);
    }

  __syncthreads();

  for (int t = 0; t < kT; ++t) {
    // convert raw -> x fragments
    f16x8 xa[2][2][2];   // [ml][ks][hl]
#pragma unroll
    for (int ml = 0; ml < 2; ++ml)
#pragma unroll
      for (int ks = 0; ks < 2; ++ks)
        split8v(raw[ml][ks][0], raw[ml][ks][1], xa[ml][ks][0], xa[ml][ks][1]);
    // prefetch x(t+1)
    if (t + 1 < kT) {
#pragma unroll
      for (int ml = 0; ml < 2; ++ml)
#pragma unroll
        for (int ks = 0; ks < 2; ++ks) {
          const float* p = xin + ((size_t)(t + 1) * kBN + s0 + (2 * mh + ml) * 16 + i) * 64 + ks * 32 + q * 8;
          raw[ml][ks][0] = *(const float4*)p;
          raw[ml][ks][1] = *(const float4*)(p + 4);
        }
    }
    // read h fragments (gen t-1)
    f16x8 ha[2][2][2];
    if (t > 0) {
#pragma unroll
      for (int ml = 0; ml < 2; ++ml)
#pragma unroll
        for (int ks = 0; ks < 2; ++ks) {
          ha[ml][ks][0] = *(const f16x8*)&hfrag[2 * mh + ml][ks][0][lane * 8];
          ha[ml][ks][1] = *(const f16x8*)&hfrag[2 * mh + ml][ks][1][lane * 8];
        }
    } else {
#pragma unroll
      for (int ml = 0; ml < 2; ++ml)
#pragma unroll
        for (int ks = 0; ks < 2; ++ks) {
          ha[ml][ks][0] = (f16x8)0;
          ha[ml][ks][1] = (f16x8)0;
        }
    }
    __syncthreads();   // all waves done reading hfrag(t-1)

    f32x4 acc[2][4];   // [ml][gate]
#pragma unroll
    for (int ml = 0; ml < 2; ++ml)
#pragma unroll
      for (int g = 0; g < 4; ++g) {
        acc[ml][g][0] = bias4[g]; acc[ml][g][1] = bias4[g];
        acc[ml][g][2] = bias4[g]; acc[ml][g][3] = bias4[g];
      }
#pragma unroll
    for (int g = 0; g < 4; ++g) {
      int nt = g * 4 + cb;
      f16x8 bf[2][2][2];   // [mat][ks][hl]
#pragma unroll
      for (int mat = 0; mat < 2; ++mat)
#pragma unroll
        for (int ks = 0; ks < 2; ++ks) {
          bf[mat][ks][0] = *(const f16x8*)&wfrag[mat][0][nt][ks][lane * 8];
          bf[mat][ks][1] = *(const f16x8*)&wfrag[mat][1][nt][ks][lane * 8];
        }
#pragma unroll
      for (int ml = 0; ml < 2; ++ml) {
        f32x4 a = acc[ml][g];
#pragma unroll
        for (int ks = 0; ks < 2; ++ks) {
          a = __builtin_amdgcn_mfma_f32_16x16x32_f16(xa[ml][ks][0], bf[0][ks][0], a, 0, 0, 0);
          a = __builtin_amdgcn_mfma_f32_16x16x32_f16(xa[ml][ks][0], bf[0][ks][1], a, 0, 0, 0);
          a = __builtin_amdgcn_mfma_f32_16x16x32_f16(xa[ml][ks][1], bf[0][ks][0], a, 0, 0, 0);
          a = __builtin_amdgcn_mfma_f32_16x16x32_f16(ha[ml][ks][0], bf[1][ks][0], a, 0, 0, 0);
          a = __builtin_amdgcn_mfma_f32_16x16x32_f16(ha[ml][ks][0], bf[1][ks][1], a, 0, 0, 0);
          a = __builtin_amdgcn_mfma_f32_16x16x32_f16(ha[ml][ks][1], bf[1][ks][0], a, 0, 0, 0);
        }
        acc[ml][g] = a;
      }
    }

#pragma unroll
    for (int ml = 0; ml < 2; ++ml)
#pragma unroll
      for (int r = 0; r < 4; ++r) {
        float zi = acc[ml][0][r], zf = acc[ml][1][r];
        float zg = acc[ml][2][r], zo = acc[ml][3][r];
        float ig = sigm(zi), fg = sigm(zf), gg = tanh_(zg), og = sigm(zo);
        float c = fg * cstate[ml][r] + ig * gg;
        cstate[ml][r] = c;
        float hv = og * tanh_(c);
        int row = q * 4 + r;
        int Mt = 2 * mh + ml;
        xout[((size_t)t * kBN + s0 + Mt * 16 + row) * 64 + ch] = hv;
        _Float16 hh = (_Float16)hv;
        int lane2 = q2 * 16 + row;
        hfrag[Mt][ks2][0][lane2 * 8 + j2] = hh;
        hfrag[Mt][ks2][1][lane2 * 8 + j2] = (_Float16)(hv - (float)hh);
      }
    __syncthreads();   // hfrag(t) visible before t+1 reads
  }
}

// ---------------------------------------------------------------------------
// Weight-fragment stagers for the head (B-frag order, fp16 hi/lo).
// ---------------------------------------------------------------------------
__device__ __forceinline__ void stage_frags64(const float* W, _Float16* base,
                                              int O, int tid) {
  int total = O * 16;
  for (int idx = tid; idx < total; idx += 256) {
    int r = idx >> 4, k4 = idx & 15;
    float4 v = *(const float4*)&W[r * 64 + k4 * 4];
    int k = k4 * 4;
    int nt = r >> 4, ii = r & 15, ks = k >> 5, qq = (k >> 3) & 3, j0 = k & 7;
    _Float16* dh = base + ((nt * 2 + ks) * 2) * 512 + (qq * 16 + ii) * 8 + j0;
    _Float16* dl = dh + 512;
    float vv[4] = {v.x, v.y, v.z, v.w};
#pragma unroll
    for (int u = 0; u < 4; ++u) {
      _Float16 hh = (_Float16)vv[u];
      dh[u] = hh;
      dl[u] = (_Float16)(vv[u] - (float)hh);
    }
  }
}

__device__ __forceinline__ void stage_frags128(const float* W, _Float16* base,
                                               int O, int tid) {
  int total = O * 32;
  for (int idx = tid; idx < total; idx += 256) {
    int r = idx >> 5, k4 = idx & 31;
    float4 v = *(const float4*)&W[r * 128 + k4 * 4];
    int k = k4 * 4;
    int nt = r >> 4, ii = r & 15, ks = k >> 5, qq = (k >> 3) & 3, j0 = k & 7;
    _Float16* dh = base + ((nt * 4 + ks) * 2) * 512 + (qq * 16 + ii) * 8 + j0;
    _Float16* dl = dh + 512;
    float vv[4] = {v.x, v.y, v.z, v.w};
#pragma unroll
    for (int u = 0; u < 4; ++u) {
      _Float16 hh = (_Float16)vv[u];
      dh[u] = hh;
      dl[u] = (_Float16)(vv[u] - (float)hh);
    }
  }
}

// ---------------------------------------------------------------------------
// Stage 4 v2: fused attention + head MLP, all GEMMs via fp16x3 MFMA.
// ---------------------------------------------------------------------------
__global__ __launch_bounds__(256, 1) void head_kernel(
    const float* __restrict__ x, const float* __restrict__ win,
    const float* __restrict__ bin, const float* __restrict__ wout,
    const float* __restrict__ bout, const float* __restrict__ pw1,
    const float* __restrict__ pb1, const float* __restrict__ pw2,
    const float* __restrict__ pb2, const float* __restrict__ pw3,
    const float* __restrict__ pb3, float* __restrict__ out) {
  __shared__ __align__(16) float smem[30720];   // 120 KB
  _Float16* wb = (_Float16*)smem;               // 84 KB weight frags
  float* buf = smem + 21504;                    // 36 KB activations

  int tid = threadIdx.x;
  int w = tid >> 6, lane = tid & 63;
  int q = lane >> 4, i = lane & 15;
  int s0 = blockIdx.x * 64;

  stage_frags64(win, wb, 64, tid);                 // Wq
  stage_frags64(win + 64 * 64, wb + 8192, 128, tid);  // Wkv
  __syncthreads();

  // ---- q projection at t=15 ----
  {
    f16x8 ah[2], al[2];
#pragma unroll
    for (int ks = 0; ks < 2; ++ks)
      split8(x + ((size_t)15 * kBN + s0 + w * 16 + i) * 64 + ks * 32 + q * 8,
             ah[ks], al[ks]);
#pragma unroll
    for (int nt = 0; nt < 4; ++nt) {
      float bias = bin[nt * 16 + i];
      f32x4 acc = {bias, bias, bias, bias};
#pragma unroll
      for (int ks = 0; ks < 2; ++ks) {
        const _Float16* bp = wb + ((nt * 2 + ks) * 2) * 512 + lane * 8;
        acc = mm3(ah[ks], al[ks], *(const f16x8*)bp, *(const f16x8*)(bp + 512), acc);
      }
      *(float4*)&buf[(nt * 16 + i) * 68 + w * 16 + q * 4] = *(float4*)&acc;
    }
  }
  __syncthreads();
  float qreg[16];
#pragma unroll
  for (int d = 0; d < 16; ++d) qreg[d] = buf[(w * 16 + d) * 68 + lane];
  __syncthreads();

  // ---- t loop: kv projection via MFMA + online-softmax attention ----
  float m = -1e30f, l = 0.f;
  float o[16];
#pragma unroll
  for (int d = 0; d < 16; ++d) o[d] = 0.f;

  for (int t = 0; t < kT; ++t) {
    f16x8 xah[4][2], xal[4][2];
#pragma unroll
    for (int Mt = 0; Mt < 4; ++Mt)
#pragma unroll
      for (int ks = 0; ks < 2; ++ks)
        split8(x + ((size_t)t * kBN + s0 + Mt * 16 + i) * 64 + ks * 32 + q * 8,
               xah[Mt][ks], xal[Mt][ks]);
#pragma unroll
    for (int u = 0; u < 2; ++u) {
      int nt = 2 * w + u;                    // cols 0..63 = k, 64..127 = v
      float bias = bin[64 + nt * 16 + i];
      f16x8 bh[2], bl[2];
#pragma unroll
      for (int ks = 0; ks < 2; ++ks) {
        const _Float16* bp = wb + 8192 + ((nt * 2 + ks) * 2) * 512 + lane * 8;
        bh[ks] = *(const f16x8*)bp;
        bl[ks] = *(const f16x8*)(bp + 512);
      }
#pragma unroll
      for (int Mt = 0; Mt < 4; ++Mt) {
        f32x4 acc = {bias, bias, bias, bias};
#pragma unroll
        for (int ks = 0; ks < 2; ++ks)
          acc = mm3(xah[Mt][ks], xal[Mt][ks], bh[ks], bl[ks], acc);
        *(float4*)&buf[(nt * 16 + i) * 68 + Mt * 16 + q * 4] = *(float4*)&acc;
      }
    }
    __syncthreads();
    float sc = 0.f;
#pragma unroll
    for (int d = 0; d < 16; ++d) sc += qreg[d] * buf[(w * 16 + d) * 68 + lane];
    sc *= 0.25f;   // 1/sqrt(HD=16)
    float mn = fmaxf(m, sc);
    float alpha = __expf(m - mn);
    float p = __expf(sc - mn);
    l = l * alpha + p;
#pragma unroll
    for (int d = 0; d < 16; ++d)
      o[d] = o[d] * alpha + p * buf[(64 + w * 16 + d) * 68 + lane];
    m = mn;
    __syncthreads();
  }

  // ---- write normalized o (transposed, cols 0..63) ----
  float linv = 1.f / l;
#pragma unroll
  for (int d = 0; d < 16; ++d) buf[(w * 16 + d) * 68 + lane] = o[d] * linv;
  __syncthreads();

  // ---- restage phase-B weights ----
  stage_frags64(wout, wb, 64, tid);
  stage_frags64(pw1, wb + 8192, 128, tid);
  stage_frags128(pw2, wb + 24576, 64, tid);
  for (int idx = tid; idx < 256; idx += 256) {   // pw3 padded to 16 rows
    int r = idx >> 4, k4 = idx & 15;
    float4 v = {0.f, 0.f, 0.f, 0.f};
    if (r < kNC) v = *(const float4*)&pw3[r * 64 + k4 * 4];
    int k = k4 * 4;
    int ks = k >> 5, qq = (k >> 3) & 3, j0 = k & 7;
    _Float16* dh = wb + 40960 + (ks * 2) * 512 + (qq * 16 + r) * 8 + j0;
    _Float16* dl = dh + 512;
    float vv[4] = {v.x, v.y, v.z, v.w};
#pragma unroll
    for (int u = 0; u < 4; ++u) {
      _Float16 hh = (_Float16)vv[u];
      dh[u] = hh;
      dl[u] = (_Float16)(vv[u] - (float)hh);
    }
  }
  __syncthreads();

  int seq = w * 16 + i;

  // ---- out projection ----
  {
    f16x8 ah[2], al[2];
    split8T(buf, q * 8, seq, ah[0], al[0]);
    split8T(buf, 32 + q * 8, seq, ah[1], al[1]);
#pragma unroll
    for (int nt = 0; nt < 4; ++nt) {
      float bias = bout[nt * 16 + i];
      f32x4 acc = {bias, bias, bias, bias};
#pragma unroll
      for (int ks = 0; ks < 2; ++ks) {
        const _Float16* bp = wb + ((nt * 2 + ks) * 2) * 512 + lane * 8;
        acc = mm3(ah[ks], al[ks], *(const f16x8*)bp, *(const f16x8*)(bp + 512), acc);
      }
      *(float4*)&buf[4352 + (nt * 16 + i) * 68 + w * 16 + q * 4] = *(float4*)&acc;
    }
  }
  __syncthreads();

  // ---- z1 = relu(fin @ pw1^T + pb1) ----
  {
    f16x8 ah[2], al[2];
    split8T(buf + 4352, q * 8, seq, ah[0], al[0]);
    split8T(buf + 4352, 32 + q * 8, seq, ah[1], al[1]);
    __syncthreads();
#pragma unroll
    for (int nt = 0; nt < 8; ++nt) {
      float bias = pb1[nt * 16 + i];
      f32x4 acc = {bias, bias, bias, bias};
#pragma unroll
      for (int ks = 0; ks < 2; ++ks) {
        const _Float16* bp = wb + 8192 + ((nt * 2 + ks) * 2) * 512 + lane * 8;
        acc = mm3(ah[ks], al[ks], *(const f16x8*)bp, *(const f16x8*)(bp + 512), acc);
      }
      f32x4 r4;
#pragma unroll
      for (int r = 0; r < 4; ++r) r4[r] = fmaxf(acc[r], 0.f);
      *(float4*)&buf[(nt * 16 + i) * 68 + w * 16 + q * 4] = *(float4*)&r4;
    }
  }
  __syncthreads();

  // ---- z2 = relu(z1 @ pw2^T + pb2) ----
  {
    f16x8 ah[4], al[4];
#pragma unroll
    for (int ks = 0; ks < 4; ++ks)
      split8T(buf, ks * 32 + q * 8, seq, ah[ks], al[ks]);
    __syncthreads();
#pragma unroll
    for (int nt = 0; nt < 4; ++nt) {
      float bias = pb2[nt * 16 + i];
      f32x4 acc = {bias, bias, bias, bias};
#pragma unroll
      for (int ks = 0; ks < 4; ++ks) {
        const _Float16* bp = wb + 24576 + ((nt * 4 + ks) * 2) * 512 + lane * 8;
        acc = mm3(ah[ks], al[ks], *(const f16x8*)bp, *(const f16x8*)(bp + 512), acc);
      }
      f32x4 r4;
#pragma unroll
      for (int r = 0; r < 4; ++r) r4[r] = fmaxf(acc[r], 0.f);
      *(float4*)&buf[(nt * 16 + i) * 68 + w * 16 + q * 4] = *(float4*)&r4;
    }
  }
  __syncthreads();

  // ---- logits ----
  {
    f16x8 ah[2], al[2];
    split8T(buf, q * 8, seq, ah[0], al[0]);
    split8T(buf, 32 + q * 8, seq, ah[1], al[1]);
    f32x4 acc = {0.f, 0.f, 0.f, 0.f};
#pragma unroll
    for (int ks = 0; ks < 2; ++ks) {
      const _Float16* bp = wb + 40960 + (ks * 2) * 512 + lane * 8;
      acc = mm3(ah[ks], al[ks], *(const f16x8*)bp, *(const f16x8*)(bp + 512), acc);
    }
    if (i < kNC) {
      float bb = pb3[i];
#pragma unroll
      for (int r = 0; r < 4; ++r)
        out[(size_t)(s0 + w * 16 + q * 4 + r) * kNC + i] = acc[r] + bb;
    }
  }
}

// ---------------------------------------------------------------------------
extern "C" void kernel_launch(void* const* d_in, const int* in_sizes, int n_in,
                              void* d_out, int out_size, void* d_ws, size_t ws_size,
                              hipStream_t stream) {
  const float* nf    = (const float*)d_in[0];
  const int*   ei    = (const int*)d_in[1];
  const float* sc_w1 = (const float*)d_in[2];
  const float* sc_b1 = (const float*)d_in[3];
  const float* sc_w2 = (const float*)d_in[4];
  const float* sc_b2 = (const float*)d_in[5];
  const float* wih0  = (const float*)d_in[6];
  const float* whh0  = (const float*)d_in[7];
  const float* bih0  = (const float*)d_in[8];
  const float* bhh0  = (const float*)d_in[9];
  const float* wih1  = (const float*)d_in[10];
  const float* whh1  = (const float*)d_in[11];
  const float* bih1  = (const float*)d_in[12];
  const float* bhh1  = (const float*)d_in[13];
  const float* win   = (const float*)d_in[14];
  const float* bin   = (const float*)d_in[15];
  const float* wout  = (const float*)d_in[16];
  const float* bout  = (const float*)d_in[17];
  const float* pw1   = (const float*)d_in[18];
  const float* pb1   = (const float*)d_in[19];
  const float* pw2   = (const float*)d_in[20];
  const float* pb2   = (const float*)d_in[21];
  const float* pw3   = (const float*)d_in[22];
  const float* pb3   = (const float*)d_in[23];
  float* out = (float*)d_out;

  const size_t NB = (size_t)kT * kBN * 64;  // 16,777,216 floats per buffer
  float* A = (float*)d_ws;   // conv output h; later LSTM ping buffer
  float* C = A + NB;         // x after aggregation; LSTM pong buffer
  int* cnt = (int*)(C + NB);           // T*N
  int* off = cnt + kT * kN;            // T*N
  int* cur = off + kT * kN;            // T*N
  int* csr = cur + kT * kN;            // T*E

  hipMemsetAsync(cnt, 0, (size_t)kT * kN * sizeof(int), stream);

  conv_kernel<<<1024, 256, 0, stream>>>(nf, sc_w1, sc_b1, sc_w2, sc_b2, A);
  count_kernel<<<2048, 256, 0, stream>>>(ei, cnt);
  scan_kernel<<<16, 1024, 0, stream>>>(cnt, off, cur);
  place_kernel<<<2048, 256, 0, stream>>>(ei, cur, csr);
  gather_kernel<<<16384, 256, 0, stream>>>(A, csr, off, cnt, C);
  lstm_kernel<<<256, 512, 0, stream>>>(C, A, wih0, whh0, bih0, bhh0);
  lstm_kernel<<<256, 512, 0, stream>>>(A, C, wih1, whh1, bih1, bhh1);
  head_kernel<<<256, 256, 0, stream>>>(C, win, bin, wout, bout,
                                       pw1, pb1, pw2, pb2, pw3, pb3, out);
}